// Round 7
// baseline (135.748 us; speedup 1.0000x reference)
//
#include <hip/hip_runtime.h>
#include <math.h>

// Problem constants (from reference): B=64, Q=900, T=128, NUM_CLASSES=13
#define B_    64
#define Q_    900
#define T_    128
#define NCLS  13
#define NCLS1 14
#define NTH   256
#define NWV   (NTH / 64)
#define NKW   4           // block-wide scan: col q = tid + 256*k, k<NKW

// Block-wide f64 sum; result valid on tid 0. All threads must call.
__device__ __forceinline__ double blockSum(double v, double* sAcc, int tid) {
#pragma unroll
    for (int off = 32; off > 0; off >>= 1) v += __shfl_down(v, off);
    if ((tid & 63) == 0) sAcc[tid >> 6] = v;
    __syncthreads();
    if (tid == 0) {
#pragma unroll
        for (int w = 1; w < NWV; ++w) v += sAcc[w];
    }
    __syncthreads();
    return v;
}

// f32 cost entry, identical op order to the jnp reference:
// (|dx|+|dy|+|dz|+|dw| summed left-to-right) - prob[lab].
__device__ __forceinline__ float costQ(const float4 p4, const float4 t4, const float pr) {
    float cb = fabsf(p4.x - t4.x);
    cb = cb + fabsf(p4.y - t4.y);
    cb = cb + fabsf(p4.z - t4.z);
    cb = cb + fabsf(p4.w - t4.w);
    return cb - pr;
}

// ---- DPP full-wave min reductions (row_shr + row_bcast chain) ----
// Verified exact on R11/R13/R16/R20 (absmax 0). Uniform result via readlane(63).
#define DPP_ROW_SHR1 0x111
#define DPP_ROW_SHR2 0x112
#define DPP_ROW_SHR4 0x114
#define DPP_ROW_SHR8 0x118
#define DPP_BCAST15  0x142
#define DPP_BCAST31  0x143

__device__ __forceinline__ float waveMinF32(float x) {
    const int INFI = 0x7f800000;                       // +inf bits
    float f = x;
#define MRED(C) { const int o = __builtin_amdgcn_update_dpp(INFI, __float_as_int(f), C, 0xf, 0xf, false); \
                  f = fminf(f, __int_as_float(o)); }
    MRED(DPP_ROW_SHR1) MRED(DPP_ROW_SHR2) MRED(DPP_ROW_SHR4) MRED(DPP_ROW_SHR8)
    MRED(DPP_BCAST15)  MRED(DPP_BCAST31)
#undef MRED
    return __int_as_float(__builtin_amdgcn_readlane(__float_as_int(f), 63));
}

__device__ __forceinline__ int waveMinI32(int x) {
    int f = x;
#define MRED(C) { const int o = __builtin_amdgcn_update_dpp(0x7fffffff, f, C, 0xf, 0xf, false); \
                  f = (o < f) ? o : f; }
    MRED(DPP_ROW_SHR1) MRED(DPP_ROW_SHR2) MRED(DPP_ROW_SHR4) MRED(DPP_ROW_SHR8)
    MRED(DPP_BCAST15)  MRED(DPP_BCAST31)
#undef MRED
    return __builtin_amdgcn_readlane(f, 63);
}

// One block per image. History: R16/R19 94us; R20 4-wave SSP scan 69.4us
// (absmax 0) = baseline. R17 col-duals REVERTED (trajectory change). R18
// preg-mirror REVERTED (+16us real).
// This round (R21): column-indexed HEAD MIRROR. Within a search, sP and sU
// are constant (deferred-dual SSP), so sHead[q] = {t4[row], u[row], lab[row],
// rowm} built ONCE PER SEARCH is valid for all pops of that search. The pop
// then does ONE 32B broadcast read sHead[winq] instead of the dependent
// sP[winq] read (~120cy) + 3 head loads (~135cy); the current row's head
// state (t4,u0,lab) is carried in registers across pops (it=0 reads the free
// row's head directly). All values are bit-copies -> identical trajectory,
// absmax must stay 0. Rebuild: once per search (post-augment) + 1 barrier.
extern "C" __global__ __launch_bounds__(NTH, 1)
void detr_hungarian_loss(const float* __restrict__ pc,    // [B,Q,14]
                         const float* __restrict__ pbx,   // [B,Q,4]
                         const int*   __restrict__ tl,    // [B,T]
                         const float* __restrict__ tbx,   // [B,T,4]
                         float* __restrict__ out)         // [1], poisoned 0xAA
{
    const int b   = blockIdx.x;
    const int tid = threadIdx.x;

    __shared__ float  sProb[Q_ * NCLS];   // softmax probs, classes 0..12
    __shared__ float  sLse[Q_];           // logsumexp per query (for CE)
    __shared__ float4 sPb4[Q_];           // predicted boxes
    __shared__ float4 sTb4[T_];           // target boxes
    __shared__ int    sLab[T_];           // target labels
    __shared__ float  sU[T_];             // row duals (f32)
    __shared__ int    sP[Q_];             // col -> row+1, 0 = free
    __shared__ int    sWay[Q_];           // parent cols (per pass); scratch: minrow; reused as tc[]
    __shared__ int    sAmin[T_];          // row -> argmin column
    __shared__ int    sFree[T_];
    __shared__ int    sNF;
    __shared__ int    sWcnt[2];           // per-wave free counts (greedy init)
    __shared__ int    sPred[T_];          // target t -> matched query
    __shared__ float  sMv[2][NWV];        // per-wave pop minima (double-buffered)
    __shared__ int    sMq[2][NWV];
    __shared__ float4 sHeadA[Q_];         // col head mirror: t4 of matched row
    __shared__ float4 sHeadB[Q_];         // {u, bits(lab), bits(rowm), 0}
    __shared__ double sAcc[NWV];

    const float FINF = __builtin_inff();

    const float* pcb = pc  + (size_t)b * Q_ * NCLS1;
    const float* pbb = pbx + (size_t)b * Q_ * 4;
    const float* tbb = tbx + (size_t)b * T_ * 4;
    const int*   tlb = tl  + (size_t)b * T_;

    // ---- stage inputs + f32 softmax (same op order as jax.nn.softmax) ----
    for (int q = tid; q < Q_; q += NTH) {
        float x[NCLS1];
#pragma unroll
        for (int c = 0; c < NCLS1; ++c) x[c] = pcb[q * NCLS1 + c];
        float mx = x[0];
#pragma unroll
        for (int c = 1; c < NCLS1; ++c) mx = fmaxf(mx, x[c]);
        float ex[NCLS1];
        float sum = 0.f;
#pragma unroll
        for (int c = 0; c < NCLS1; ++c) { ex[c] = expf(x[c] - mx); sum += ex[c]; }
#pragma unroll
        for (int c = 0; c < NCLS; ++c) sProb[q * NCLS + c] = ex[c] / sum;
        sLse[q] = mx + logf(sum);
        sPb4[q] = reinterpret_cast<const float4*>(pbb)[q];
        sP[q] = 0;
        sWay[q] = 0x7fffffff;             // minrow scratch for greedy init
    }
    for (int t = tid; t < T_; t += NTH) {
        sLab[t] = tlb[t];
        sTb4[t] = reinterpret_cast<const float4*>(tbb)[t];
    }
    __syncthreads();

    // ---- phase 1: row minima u[r] = min_j cost[r][j] + argmin column ----
    {
        const int r    = tid >> 1;        // 0..127, two threads per row
        const int half = tid & 1;
        const float4 t4  = sTb4[r];
        const int    lab = sLab[r];
        float bv = FINF;
        int   bj = Q_;
        const int q0 = half * (Q_ / 2);
        for (int q = q0; q < q0 + (Q_ / 2); ++q) {
            const float c = costQ(sPb4[q], t4, sProb[q * NCLS + lab]);
            if (c < bv) { bv = c; bj = q; }
        }
        const float ov = __shfl_xor(bv, 1);
        const int   oj = __shfl_xor(bj, 1);
        if (ov < bv || (ov == bv && oj < bj)) { bv = ov; bj = oj; }
        if (half == 0) { sU[r] = bv; sAmin[r] = bj; }
    }
    __syncthreads();

    // ---- greedy zero-reduced-cost assignment (parallel, serial-equivalent;
    // verified exact in R16/R19/R20): row r wins col sAmin[r] iff r is the
    // min proposing row. Free list in increasing r via ballot prefix. ----
    bool isfree = false; int fpos = 0;
    if (tid < T_) atomicMin(&sWay[sAmin[tid]], tid);
    __syncthreads();
    if (tid < T_) {
        const int j = sAmin[tid];
        isfree = (sWay[j] != tid);
        if (!isfree) sP[j] = tid + 1;
        const unsigned long long bal = __ballot(isfree);
        const int lane = tid & 63;
        fpos = __popcll(bal & ((1ull << (unsigned)lane) - 1ull));
        if (lane == 0) sWcnt[tid >> 6] = (int)__popcll(bal);
    }
    __syncthreads();
    if (tid < T_ && isfree) {
        const int off = (tid >> 6) ? sWcnt[0] : 0;
        sFree[off + fpos] = tid;
    }
    if (tid == 0) sNF = sWcnt[0] + sWcnt[1];
    __syncthreads();

    // ============ block-wide deferred-dual SSP (all 4 waves scan) ============
    {
        const int lane = tid & 63;
        const int wv   = tid >> 6;
        unsigned validMask = 0;
#pragma unroll
        for (int k = 0; k < NKW; ++k)
            if (tid + (k << 8) < Q_) validMask |= 1u << k;

        float4 pbq[NKW];                  // owned predicted boxes
        float  v[NKW];                    // owned column duals
#pragma unroll
        for (int k = 0; k < NKW; ++k) {
            const int q = tid + (k << 8);
            pbq[k] = (q < Q_) ? sPb4[q] : make_float4(0.f, 0.f, 0.f, 0.f);
            v[k] = 0.f;
        }
        const int nf = sNF;

        // build head mirror for owned columns (valid while sP/sU unchanged)
#define BUILD_HEAD()                                                          \
        {                                                                     \
            _Pragma("unroll")                                                 \
            for (int k = 0; k < NKW; ++k) {                                   \
                const int q = tid + (k << 8);                                 \
                if (q < Q_) {                                                 \
                    const int pv = sP[q];                                     \
                    if (pv > 0) {                                             \
                        const int r = pv - 1;                                 \
                        sHeadA[q] = sTb4[r];                                  \
                        sHeadB[q] = make_float4(sU[r],                        \
                                                __int_as_float(sLab[r]),      \
                                                __int_as_float(pv), 0.f);     \
                    } else {                                                  \
                        sHeadB[q] = make_float4(0.f, 0.f,                     \
                                                __int_as_float(0), 0.f);      \
                    }                                                         \
                }                                                             \
            }                                                                 \
        }

        BUILD_HEAD();
        __syncthreads();

        for (int fi = 0; fi < nf; ++fi) {
            const int rf = sFree[fi];
            float minv[NKW];
            int   way[NKW];
#pragma unroll
            for (int k = 0; k < NKW; ++k) { minv[k] = FINF; way[k] = -1; }
            unsigned usedM   = ~validMask & ((1u << NKW) - 1u);
            unsigned poppedM = 0;
            // current row head state, carried in registers across pops
            float  u0  = sU[rf];
            float4 t4  = sTb4[rf];
            int    lab = sLab[rf];
            float dcur  = 0.f;
            int   jprev = -1;             // root marker
            float dT = 0.f; int jT = -1;
            int   buf = 0;

            for (int it = 0; it < 200; ++it) {
                const float base = dcur - u0;

                float bestv = FINF;
                int   bestq = 1 << 29;
#pragma unroll
                for (int k = 0; k < NKW; ++k) {
                    if (!((usedM >> k) & 1u)) {
                        const int   q    = tid + (k << 8);
                        const float cost = costQ(pbq[k], t4, sProb[q * NCLS + lab]);
                        const float cur  = base + (cost - v[k]);   // R6 association
                        if (cur < minv[k]) { minv[k] = cur; way[k] = jprev; }
                        if (minv[k] < bestv) { bestv = minv[k]; bestq = q; }
                    }
                }
                // per-wave min: DPP value-min + ballot fast path; ties ->
                // exact i32 DPP min (smallest column within the wave).
                const float wval = waveMinF32(bestv);
                const unsigned long long tm = __ballot(bestv == wval);
                int wq;
                if (__popcll(tm) == 1) {
                    wq = __builtin_amdgcn_readlane(bestq, (int)__builtin_ctzll(tm));
                } else {
                    const int cand = (bestv == wval) ? bestq : 0x7fffffff;
                    wq = waveMinI32(cand);
                }
                if (lane == 0) { sMv[buf][wv] = wval; sMq[buf][wv] = wq; }
                __syncthreads();
                // global winner, computed redundantly+uniformly by all:
                // min value, smallest column on value ties (np.argmin).
                float gv = FINF; int gq = 0x7fffffff;
#pragma unroll
                for (int w = 0; w < NWV; ++w) {
                    const float vw = sMv[buf][w];
                    const int   qw = sMq[buf][w];
                    if (vw < gv)              { gv = vw; gq = qw; }
                    else if (vw == gv && qw < gq) gq = qw;
                }
                const float winv = gv;
                const int   winq = gq;

                if (tid == (winq & 255)) usedM |= 1u << (winq >> 8);  // freeze
                // ONE broadcast 32B read gives rowm + next row's head state
                const float4 hA = sHeadA[winq];
                const float4 hB = sHeadB[winq];
                const int rowm = __float_as_int(hB.z);
                if (rowm == 0) { dT = winv; jT = winq; break; }   // free col: done
                if (tid == (winq & 255)) poppedM |= 1u << (winq >> 8);
                jprev = winq; dcur = winv; buf ^= 1;
                t4 = hA; u0 = hB.x; lab = __float_as_int(hB.y);
            }

            // flush way regs (augment only reads cols improved this pass)
#pragma unroll
            for (int k = 0; k < NKW; ++k) {
                if ((validMask >> k) & 1u) sWay[tid + (k << 8)] = way[k];
            }
            // deferred dual updates (== e-maxx incremental totals), pre-augment;
            // popped columns have distinct assigned rows -> race-free.
#pragma unroll
            for (int k = 0; k < NKW; ++k) {
                if ((poppedM >> k) & 1u) {
                    const int q   = tid + (k << 8);
                    const int row = sP[q] - 1;
                    sU[row] += dT - minv[k];
                    v[k]    += minv[k] - dT;
                }
            }
            if (tid == 0) sU[rf] += dT;
            __syncthreads();
            if (tid == 0 && jT >= 0) {                // augment along parents
                int jj = jT, guard = 0;
                while (guard++ < 200) {
                    const int jp = sWay[jj];
                    if (jp < 0) { sP[jj] = rf + 1; break; }
                    sP[jj] = sP[jp];
                    jj = jp;
                }
            }
            __syncthreads();
            BUILD_HEAD();                 // refresh mirror from new sP/sU
            __syncthreads();
        }
#undef BUILD_HEAD
    }
    __syncthreads();

    // ---- extract matching: pred query for each target ----
    for (int q = tid; q < Q_; q += NTH) {
        const int pi = sP[q];
        if (pi > 0) sPred[pi - 1] = q;
    }
    __syncthreads();

    // ---- tc[] (reuse sWay): NUM_CLASSES default, matched queries get label ----
    int* sTc = sWay;
    for (int q = tid; q < Q_; q += NTH) sTc[q] = NCLS;
    __syncthreads();
    for (int t = tid; t < T_; t += NTH) sTc[sPred[t]] = sLab[t];  // sPred distinct
    __syncthreads();

    // ---- weighted CE over all queries ----
    double swn = 0.0, sw = 0.0;
    for (int q = tid; q < Q_; q += NTH) {
        const int   c   = sTc[q];
        const float xv  = pcb[q * NCLS1 + c];
        const float nll = sLse[q] - xv;              // -log_softmax[tc]
        const double w  = (c == NCLS) ? (double)0.05f : 1.0;
        swn += w * (double)nll;
        sw  += w;
    }

    // ---- bbox L1 + GIoU over matched pairs ----
    double l1s = 0.0, gs = 0.0;
    for (int t = tid; t < T_; t += NTH) {
        const int q = sPred[t];
        const float4 p4 = sPb4[q];
        const float4 t4 = sTb4[t];
        l1s += (double)fabsf(p4.x - t4.x) + (double)fabsf(p4.y - t4.y)
             + (double)fabsf(p4.z - t4.z) + (double)fabsf(p4.w - t4.w);
        const float ax1 = p4.x - 0.5f * p4.z, ay1 = p4.y - 0.5f * p4.w;
        const float ax2 = p4.x + 0.5f * p4.z, ay2 = p4.y + 0.5f * p4.w;
        const float bx1 = t4.x - 0.5f * t4.z, by1 = t4.y - 0.5f * t4.w;
        const float bx2 = t4.x + 0.5f * t4.z, by2 = t4.y + 0.5f * t4.w;
        const double a1 = (double)(ax2 - ax1) * (double)(ay2 - ay1);
        const double a2 = (double)(bx2 - bx1) * (double)(by2 - by1);
        const double ltx = fmax((double)ax1, (double)bx1);
        const double lty = fmax((double)ay1, (double)by1);
        const double rbx = fmin((double)ax2, (double)bx2);
        const double rby = fmin((double)ay2, (double)by2);
        const double iw = fmax(rbx - ltx, 0.0), ih = fmax(rby - lty, 0.0);
        const double inter = iw * ih;
        const double uni   = a1 + a2 - inter;
        const double iou   = inter / uni;
        const double cx1 = fmin((double)ax1, (double)bx1);
        const double cy1 = fmin((double)ay1, (double)by1);
        const double cx2 = fmax((double)ax2, (double)bx2);
        const double cy2 = fmax((double)ay2, (double)by2);
        const double ac  = (cx2 - cx1) * (cy2 - cy1);
        const double giou = iou - (ac - uni) / ac;
        gs += 1.0 - giou;
    }

    const double swnT = blockSum(swn, sAcc, tid);
    const double swT  = blockSum(sw,  sAcc, tid);
    const double l1T  = blockSum(l1s, sAcc, tid);
    const double gsT  = blockSum(gs,  sAcc, tid);
    if (tid == 0) {
        const double cls = swnT / swT;
        const double bb  = 5.0 * (l1T / (double)(T_ * 4)) + 2.0 * (gsT / (double)T_);
        const double mine = (cls + bb) / 8192.0;
        // fused finalize: CAS converts the 0xAA poison to 0.0 exactly once
        // (each block CASes before its own add; no spin), then atomic f32 sum.
        atomicCAS((unsigned int*)out, 0xAAAAAAAAu, 0u);
        atomicAdd(out, (float)mine);
    }
}

extern "C" void kernel_launch(void* const* d_in, const int* in_sizes, int n_in,
                              void* d_out, int out_size, void* d_ws, size_t ws_size,
                              hipStream_t stream) {
    const float* pc  = (const float*)d_in[0];   // predicted_class [64,900,14]
    const float* pbx = (const float*)d_in[1];   // predicted_bbox  [64,900,4]
    const int*   tl  = (const int*)  d_in[2];   // target_labels   [64,128]
    const float* tbx = (const float*)d_in[3];   // target_boxes    [64,128,4]
    (void)in_sizes; (void)n_in; (void)out_size; (void)d_ws; (void)ws_size;

    detr_hungarian_loss<<<dim3(B_), dim3(NTH), 0, stream>>>(pc, pbx, tl, tbx,
                                                            (float*)d_out);
}

// Round 8
// 126.405 us; speedup vs baseline: 1.0739x; 1.0739x over previous
//
#include <hip/hip_runtime.h>
#include <math.h>

// Problem constants (from reference): B=64, Q=900, T=128, NUM_CLASSES=13
#define B_    64
#define Q_    900
#define T_    128
#define NCLS  13
#define NCLS1 14
#define NTH   256
#define NWV   (NTH / 64)
#define NKW   4           // block-wide scan: col q = tid + 256*k, k<NKW

// Block-wide f64 sum; result valid on tid 0. All threads must call.
__device__ __forceinline__ double blockSum(double v, double* sAcc, int tid) {
#pragma unroll
    for (int off = 32; off > 0; off >>= 1) v += __shfl_down(v, off);
    if ((tid & 63) == 0) sAcc[tid >> 6] = v;
    __syncthreads();
    if (tid == 0) {
#pragma unroll
        for (int w = 1; w < NWV; ++w) v += sAcc[w];
    }
    __syncthreads();
    return v;
}

// f32 cost entry, identical op order to the jnp reference:
// (|dx|+|dy|+|dz|+|dw| summed left-to-right) - prob[lab].
__device__ __forceinline__ float costQ(const float4 p4, const float4 t4, const float pr) {
    float cb = fabsf(p4.x - t4.x);
    cb = cb + fabsf(p4.y - t4.y);
    cb = cb + fabsf(p4.z - t4.z);
    cb = cb + fabsf(p4.w - t4.w);
    return cb - pr;
}

// ---- DPP full-wave min reductions (row_shr + row_bcast chain) ----
// Verified exact on R11/R13/R16/R20 (absmax 0). Uniform result via readlane(63).
#define DPP_ROW_SHR1 0x111
#define DPP_ROW_SHR2 0x112
#define DPP_ROW_SHR4 0x114
#define DPP_ROW_SHR8 0x118
#define DPP_BCAST15  0x142
#define DPP_BCAST31  0x143

__device__ __forceinline__ float waveMinF32(float x) {
    const int INFI = 0x7f800000;                       // +inf bits
    float f = x;
#define MRED(C) { const int o = __builtin_amdgcn_update_dpp(INFI, __float_as_int(f), C, 0xf, 0xf, false); \
                  f = fminf(f, __int_as_float(o)); }
    MRED(DPP_ROW_SHR1) MRED(DPP_ROW_SHR2) MRED(DPP_ROW_SHR4) MRED(DPP_ROW_SHR8)
    MRED(DPP_BCAST15)  MRED(DPP_BCAST31)
#undef MRED
    return __int_as_float(__builtin_amdgcn_readlane(__float_as_int(f), 63));
}

__device__ __forceinline__ int waveMinI32(int x) {
    int f = x;
#define MRED(C) { const int o = __builtin_amdgcn_update_dpp(0x7fffffff, f, C, 0xf, 0xf, false); \
                  f = (o < f) ? o : f; }
    MRED(DPP_ROW_SHR1) MRED(DPP_ROW_SHR2) MRED(DPP_ROW_SHR4) MRED(DPP_ROW_SHR8)
    MRED(DPP_BCAST15)  MRED(DPP_BCAST31)
#undef MRED
    return __builtin_amdgcn_readlane(f, 63);
}

// One block per image. History: R16/R19 94us; R20 4-wave SSP scan 69.4us
// (absmax 0) = baseline. REVERTED: R17 col-duals (trajectory change), R18
// preg-mirror (+16us), R21 head-mirror (+10us: per-search rebuild with
// scattered gathers costs more than the saved dependent hop). Lesson: no
// added bookkeeping structures; only overlap existing work.
// This round (R22): CANDIDATE sP PREFETCH. Right after the pop barrier, the
// 4 per-wave winner columns are known; issue 4 independent sP[cand] reads in
// parallel with the winner-select compare chain, then select rowm with the
// same unrolled (static-index) chain. Overlaps the ~120cy dependent sP read
// with the ~100cy select -> saves ~100cy/pop. Values bit-identical, uniform
// across threads -> same trajectory, absmax 0.
extern "C" __global__ __launch_bounds__(NTH, 1)
void detr_hungarian_loss(const float* __restrict__ pc,    // [B,Q,14]
                         const float* __restrict__ pbx,   // [B,Q,4]
                         const int*   __restrict__ tl,    // [B,T]
                         const float* __restrict__ tbx,   // [B,T,4]
                         float* __restrict__ out)         // [1], poisoned 0xAA
{
    const int b   = blockIdx.x;
    const int tid = threadIdx.x;

    __shared__ float  sProb[Q_ * NCLS];   // softmax probs, classes 0..12
    __shared__ float  sLse[Q_];           // logsumexp per query (for CE)
    __shared__ float4 sPb4[Q_];           // predicted boxes
    __shared__ float4 sTb4[T_];           // target boxes
    __shared__ int    sLab[T_];           // target labels
    __shared__ float  sU[T_];             // row duals (f32)
    __shared__ int    sP[Q_];             // col -> row+1, 0 = free
    __shared__ int    sWay[Q_];           // parent cols (per pass); scratch: minrow; reused as tc[]
    __shared__ int    sAmin[T_];          // row -> argmin column
    __shared__ int    sFree[T_];
    __shared__ int    sNF;
    __shared__ int    sWcnt[2];           // per-wave free counts (greedy init)
    __shared__ int    sPred[T_];          // target t -> matched query
    __shared__ float  sMv[2][NWV];        // per-wave pop minima (double-buffered)
    __shared__ int    sMq[2][NWV];
    __shared__ double sAcc[NWV];

    const float FINF = __builtin_inff();

    const float* pcb = pc  + (size_t)b * Q_ * NCLS1;
    const float* pbb = pbx + (size_t)b * Q_ * 4;
    const float* tbb = tbx + (size_t)b * T_ * 4;
    const int*   tlb = tl  + (size_t)b * T_;

    // ---- stage inputs + f32 softmax (same op order as jax.nn.softmax) ----
    for (int q = tid; q < Q_; q += NTH) {
        float x[NCLS1];
#pragma unroll
        for (int c = 0; c < NCLS1; ++c) x[c] = pcb[q * NCLS1 + c];
        float mx = x[0];
#pragma unroll
        for (int c = 1; c < NCLS1; ++c) mx = fmaxf(mx, x[c]);
        float ex[NCLS1];
        float sum = 0.f;
#pragma unroll
        for (int c = 0; c < NCLS1; ++c) { ex[c] = expf(x[c] - mx); sum += ex[c]; }
#pragma unroll
        for (int c = 0; c < NCLS; ++c) sProb[q * NCLS + c] = ex[c] / sum;
        sLse[q] = mx + logf(sum);
        sPb4[q] = reinterpret_cast<const float4*>(pbb)[q];
        sP[q] = 0;
        sWay[q] = 0x7fffffff;             // minrow scratch for greedy init
    }
    for (int t = tid; t < T_; t += NTH) {
        sLab[t] = tlb[t];
        sTb4[t] = reinterpret_cast<const float4*>(tbb)[t];
    }
    __syncthreads();

    // ---- phase 1: row minima u[r] = min_j cost[r][j] + argmin column ----
    {
        const int r    = tid >> 1;        // 0..127, two threads per row
        const int half = tid & 1;
        const float4 t4  = sTb4[r];
        const int    lab = sLab[r];
        float bv = FINF;
        int   bj = Q_;
        const int q0 = half * (Q_ / 2);
        for (int q = q0; q < q0 + (Q_ / 2); ++q) {
            const float c = costQ(sPb4[q], t4, sProb[q * NCLS + lab]);
            if (c < bv) { bv = c; bj = q; }
        }
        const float ov = __shfl_xor(bv, 1);
        const int   oj = __shfl_xor(bj, 1);
        if (ov < bv || (ov == bv && oj < bj)) { bv = ov; bj = oj; }
        if (half == 0) { sU[r] = bv; sAmin[r] = bj; }
    }
    __syncthreads();

    // ---- greedy zero-reduced-cost assignment (parallel, serial-equivalent;
    // verified exact in R16/R19/R20): row r wins col sAmin[r] iff r is the
    // min proposing row. Free list in increasing r via ballot prefix. ----
    bool isfree = false; int fpos = 0;
    if (tid < T_) atomicMin(&sWay[sAmin[tid]], tid);
    __syncthreads();
    if (tid < T_) {
        const int j = sAmin[tid];
        isfree = (sWay[j] != tid);
        if (!isfree) sP[j] = tid + 1;
        const unsigned long long bal = __ballot(isfree);
        const int lane = tid & 63;
        fpos = __popcll(bal & ((1ull << (unsigned)lane) - 1ull));
        if (lane == 0) sWcnt[tid >> 6] = (int)__popcll(bal);
    }
    __syncthreads();
    if (tid < T_ && isfree) {
        const int off = (tid >> 6) ? sWcnt[0] : 0;
        sFree[off + fpos] = tid;
    }
    if (tid == 0) sNF = sWcnt[0] + sWcnt[1];
    __syncthreads();

    // ============ block-wide deferred-dual SSP (all 4 waves scan) ============
    {
        const int lane = tid & 63;
        const int wv   = tid >> 6;
        unsigned validMask = 0;
#pragma unroll
        for (int k = 0; k < NKW; ++k)
            if (tid + (k << 8) < Q_) validMask |= 1u << k;

        float4 pbq[NKW];                  // owned predicted boxes
        float  v[NKW];                    // owned column duals
#pragma unroll
        for (int k = 0; k < NKW; ++k) {
            const int q = tid + (k << 8);
            pbq[k] = (q < Q_) ? sPb4[q] : make_float4(0.f, 0.f, 0.f, 0.f);
            v[k] = 0.f;
        }
        const int nf = sNF;

        for (int fi = 0; fi < nf; ++fi) {
            const int rf = sFree[fi];
            float minv[NKW];
            int   way[NKW];
#pragma unroll
            for (int k = 0; k < NKW; ++k) { minv[k] = FINF; way[k] = -1; }
            unsigned usedM   = ~validMask & ((1u << NKW) - 1u);
            unsigned poppedM = 0;
            int   i0row = rf;
            float dcur  = 0.f;
            int   jprev = -1;             // root marker
            float dT = 0.f; int jT = -1;
            int   buf = 0;

            for (int it = 0; it < 200; ++it) {
                const float  u0   = sU[i0row];
                const float4 t4   = sTb4[i0row];
                const int    lab  = sLab[i0row];
                const float  base = dcur - u0;

                float bestv = FINF;
                int   bestq = 1 << 29;
#pragma unroll
                for (int k = 0; k < NKW; ++k) {
                    if (!((usedM >> k) & 1u)) {
                        const int   q    = tid + (k << 8);
                        const float cost = costQ(pbq[k], t4, sProb[q * NCLS + lab]);
                        const float cur  = base + (cost - v[k]);   // R6 association
                        if (cur < minv[k]) { minv[k] = cur; way[k] = jprev; }
                        if (minv[k] < bestv) { bestv = minv[k]; bestq = q; }
                    }
                }
                // per-wave min: DPP value-min + ballot fast path; ties ->
                // exact i32 DPP min (smallest column within the wave).
                const float wval = waveMinF32(bestv);
                const unsigned long long tm = __ballot(bestv == wval);
                int wq;
                if (__popcll(tm) == 1) {
                    wq = __builtin_amdgcn_readlane(bestq, (int)__builtin_ctzll(tm));
                } else {
                    const int cand = (bestv == wval) ? bestq : 0x7fffffff;
                    wq = waveMinI32(cand);
                }
                if (lane == 0) { sMv[buf][wv] = wval; sMq[buf][wv] = wq; }
                __syncthreads();
                // prefetch sP for all 4 per-wave candidates (independent
                // reads, issued before/alongside the select chain; clamp
                // guards the impossible-in-practice all-used wave slot).
                int pq[NWV];
#pragma unroll
                for (int w = 0; w < NWV; ++w) {
                    const int qw = sMq[buf][w];
                    pq[w] = sP[((unsigned)qw < (unsigned)Q_) ? qw : 0];
                }
                // global winner + its sP value, computed redundantly and
                // uniformly by all threads: min value, smallest column on
                // ties (np.argmin semantics). Static indexing only.
                float gv = sMv[buf][0];
                int   gq = sMq[buf][0];
                int   grow = pq[0];
#pragma unroll
                for (int w = 1; w < NWV; ++w) {
                    const float vw = sMv[buf][w];
                    const int   qw = sMq[buf][w];
                    const bool better = (vw < gv) || (vw == gv && qw < gq);
                    gv   = better ? vw    : gv;
                    gq   = better ? qw    : gq;
                    grow = better ? pq[w] : grow;
                }
                const float winv = gv;
                const int   winq = gq;
                const int   rowm = grow;

                if (tid == (winq & 255)) usedM |= 1u << (winq >> 8);  // freeze
                if (rowm == 0) { dT = winv; jT = winq; break; }   // free col: done
                if (tid == (winq & 255)) poppedM |= 1u << (winq >> 8);
                jprev = winq; i0row = rowm - 1; dcur = winv; buf ^= 1;
            }

            // flush way regs (augment only reads cols improved this pass)
#pragma unroll
            for (int k = 0; k < NKW; ++k) {
                if ((validMask >> k) & 1u) sWay[tid + (k << 8)] = way[k];
            }
            // deferred dual updates (== e-maxx incremental totals), pre-augment;
            // popped columns have distinct assigned rows -> race-free.
#pragma unroll
            for (int k = 0; k < NKW; ++k) {
                if ((poppedM >> k) & 1u) {
                    const int q   = tid + (k << 8);
                    const int row = sP[q] - 1;
                    sU[row] += dT - minv[k];
                    v[k]    += minv[k] - dT;
                }
            }
            if (tid == 0) sU[rf] += dT;
            __syncthreads();
            if (tid == 0 && jT >= 0) {                // augment along parents
                int jj = jT, guard = 0;
                while (guard++ < 200) {
                    const int jp = sWay[jj];
                    if (jp < 0) { sP[jj] = rf + 1; break; }
                    sP[jj] = sP[jp];
                    jj = jp;
                }
            }
            __syncthreads();
        }
    }
    __syncthreads();

    // ---- extract matching: pred query for each target ----
    for (int q = tid; q < Q_; q += NTH) {
        const int pi = sP[q];
        if (pi > 0) sPred[pi - 1] = q;
    }
    __syncthreads();

    // ---- tc[] (reuse sWay): NUM_CLASSES default, matched queries get label ----
    int* sTc = sWay;
    for (int q = tid; q < Q_; q += NTH) sTc[q] = NCLS;
    __syncthreads();
    for (int t = tid; t < T_; t += NTH) sTc[sPred[t]] = sLab[t];  // sPred distinct
    __syncthreads();

    // ---- weighted CE over all queries ----
    double swn = 0.0, sw = 0.0;
    for (int q = tid; q < Q_; q += NTH) {
        const int   c   = sTc[q];
        const float xv  = pcb[q * NCLS1 + c];
        const float nll = sLse[q] - xv;              // -log_softmax[tc]
        const double w  = (c == NCLS) ? (double)0.05f : 1.0;
        swn += w * (double)nll;
        sw  += w;
    }

    // ---- bbox L1 + GIoU over matched pairs ----
    double l1s = 0.0, gs = 0.0;
    for (int t = tid; t < T_; t += NTH) {
        const int q = sPred[t];
        const float4 p4 = sPb4[q];
        const float4 t4 = sTb4[t];
        l1s += (double)fabsf(p4.x - t4.x) + (double)fabsf(p4.y - t4.y)
             + (double)fabsf(p4.z - t4.z) + (double)fabsf(p4.w - t4.w);
        const float ax1 = p4.x - 0.5f * p4.z, ay1 = p4.y - 0.5f * p4.w;
        const float ax2 = p4.x + 0.5f * p4.z, ay2 = p4.y + 0.5f * p4.w;
        const float bx1 = t4.x - 0.5f * t4.z, by1 = t4.y - 0.5f * t4.w;
        const float bx2 = t4.x + 0.5f * t4.z, by2 = t4.y + 0.5f * t4.w;
        const double a1 = (double)(ax2 - ax1) * (double)(ay2 - ay1);
        const double a2 = (double)(bx2 - bx1) * (double)(by2 - by1);
        const double ltx = fmax((double)ax1, (double)bx1);
        const double lty = fmax((double)ay1, (double)by1);
        const double rbx = fmin((double)ax2, (double)bx2);
        const double rby = fmin((double)ay2, (double)by2);
        const double iw = fmax(rbx - ltx, 0.0), ih = fmax(rby - lty, 0.0);
        const double inter = iw * ih;
        const double uni   = a1 + a2 - inter;
        const double iou   = inter / uni;
        const double cx1 = fmin((double)ax1, (double)bx1);
        const double cy1 = fmin((double)ay1, (double)by1);
        const double cx2 = fmax((double)ax2, (double)bx2);
        const double cy2 = fmax((double)ay2, (double)by2);
        const double ac  = (cx2 - cx1) * (cy2 - cy1);
        const double giou = iou - (ac - uni) / ac;
        gs += 1.0 - giou;
    }

    const double swnT = blockSum(swn, sAcc, tid);
    const double swT  = blockSum(sw,  sAcc, tid);
    const double l1T  = blockSum(l1s, sAcc, tid);
    const double gsT  = blockSum(gs,  sAcc, tid);
    if (tid == 0) {
        const double cls = swnT / swT;
        const double bb  = 5.0 * (l1T / (double)(T_ * 4)) + 2.0 * (gsT / (double)T_);
        const double mine = (cls + bb) / 8192.0;
        // fused finalize: CAS converts the 0xAA poison to 0.0 exactly once
        // (each block CASes before its own add; no spin), then atomic f32 sum.
        atomicCAS((unsigned int*)out, 0xAAAAAAAAu, 0u);
        atomicAdd(out, (float)mine);
    }
}

extern "C" void kernel_launch(void* const* d_in, const int* in_sizes, int n_in,
                              void* d_out, int out_size, void* d_ws, size_t ws_size,
                              hipStream_t stream) {
    const float* pc  = (const float*)d_in[0];   // predicted_class [64,900,14]
    const float* pbx = (const float*)d_in[1];   // predicted_bbox  [64,900,4]
    const int*   tl  = (const int*)  d_in[2];   // target_labels   [64,128]
    const float* tbx = (const float*)d_in[3];   // target_boxes    [64,128,4]
    (void)in_sizes; (void)n_in; (void)out_size; (void)d_ws; (void)ws_size;

    detr_hungarian_loss<<<dim3(B_), dim3(NTH), 0, stream>>>(pc, pbx, tl, tbx,
                                                            (float*)d_out);
}

// Round 9
// 113.717 us; speedup vs baseline: 1.1937x; 1.1116x over previous
//
#include <hip/hip_runtime.h>
#include <math.h>

// Problem constants (from reference): B=64, Q=900, T=128, NUM_CLASSES=13
#define B_    64
#define Q_    900
#define T_    128
#define NCLS  13
#define NCLS1 14
#define NTH   512
#define NWV   (NTH / 64)
#define NKW   2           // block-wide scan: col q = tid + 512*k, k<NKW

// Block-wide f64 sum; result valid on tid 0. All threads must call.
__device__ __forceinline__ double blockSum(double v, double* sAcc, int tid) {
#pragma unroll
    for (int off = 32; off > 0; off >>= 1) v += __shfl_down(v, off);
    if ((tid & 63) == 0) sAcc[tid >> 6] = v;
    __syncthreads();
    if (tid == 0) {
#pragma unroll
        for (int w = 1; w < NWV; ++w) v += sAcc[w];
    }
    __syncthreads();
    return v;
}

// f32 cost entry, identical op order to the jnp reference:
// (|dx|+|dy|+|dz|+|dw| summed left-to-right) - prob[lab].
__device__ __forceinline__ float costQ(const float4 p4, const float4 t4, const float pr) {
    float cb = fabsf(p4.x - t4.x);
    cb = cb + fabsf(p4.y - t4.y);
    cb = cb + fabsf(p4.z - t4.z);
    cb = cb + fabsf(p4.w - t4.w);
    return cb - pr;
}

// ---- DPP full-wave min reductions (row_shr + row_bcast chain) ----
// Verified exact on R11/R13/R16/R20 (absmax 0). Uniform result via readlane(63).
#define DPP_ROW_SHR1 0x111
#define DPP_ROW_SHR2 0x112
#define DPP_ROW_SHR4 0x114
#define DPP_ROW_SHR8 0x118
#define DPP_BCAST15  0x142
#define DPP_BCAST31  0x143

__device__ __forceinline__ float waveMinF32(float x) {
    const int INFI = 0x7f800000;                       // +inf bits
    float f = x;
#define MRED(C) { const int o = __builtin_amdgcn_update_dpp(INFI, __float_as_int(f), C, 0xf, 0xf, false); \
                  f = fminf(f, __int_as_float(o)); }
    MRED(DPP_ROW_SHR1) MRED(DPP_ROW_SHR2) MRED(DPP_ROW_SHR4) MRED(DPP_ROW_SHR8)
    MRED(DPP_BCAST15)  MRED(DPP_BCAST31)
#undef MRED
    return __int_as_float(__builtin_amdgcn_readlane(__float_as_int(f), 63));
}

__device__ __forceinline__ int waveMinI32(int x) {
    int f = x;
#define MRED(C) { const int o = __builtin_amdgcn_update_dpp(0x7fffffff, f, C, 0xf, 0xf, false); \
                  f = (o < f) ? o : f; }
    MRED(DPP_ROW_SHR1) MRED(DPP_ROW_SHR2) MRED(DPP_ROW_SHR4) MRED(DPP_ROW_SHR8)
    MRED(DPP_BCAST15)  MRED(DPP_BCAST31)
#undef MRED
    return __builtin_amdgcn_readlane(f, 63);
}

// One block per image. History: R16/R19 94us; R20 4-wave SSP 69.4us/123.6
// harness (absmax 0) = prior best. REVERTED: R17 (trajectory), R18 (+16us),
// R21 head-mirror (+10us), R22 sP-prefetch (+10us profiled) -- pop-chain
// micro-surgery fails consistently; the R20 pop chain is left untouched.
// This round (R23): NTH 256->512 (8 waves). Staging/row-minima/epilogue/
// dual-updates ~2x faster; SSP scan NKW 4->2; winner slots packed as float2
// so the select's LDS issue count stays flat (8x ds_read_b64). Selection,
// tie-breaks, and all f32 arithmetic bit-identical => same trajectory.
extern "C" __global__ __launch_bounds__(NTH, 1)
void detr_hungarian_loss(const float* __restrict__ pc,    // [B,Q,14]
                         const float* __restrict__ pbx,   // [B,Q,4]
                         const int*   __restrict__ tl,    // [B,T]
                         const float* __restrict__ tbx,   // [B,T,4]
                         float* __restrict__ out)         // [1], poisoned 0xAA
{
    const int b   = blockIdx.x;
    const int tid = threadIdx.x;

    __shared__ float  sProb[Q_ * NCLS];   // softmax probs, classes 0..12
    __shared__ float  sLse[Q_];           // logsumexp per query (for CE)
    __shared__ float4 sPb4[Q_];           // predicted boxes
    __shared__ float4 sTb4[T_];           // target boxes
    __shared__ int    sLab[T_];           // target labels
    __shared__ float  sU[T_];             // row duals (f32)
    __shared__ int    sP[Q_];             // col -> row+1, 0 = free
    __shared__ int    sWay[Q_];           // parent cols (per pass); scratch: minrow; reused as tc[]
    __shared__ int    sAmin[T_];          // row -> argmin column
    __shared__ int    sFree[T_];
    __shared__ int    sNF;
    __shared__ int    sWcnt[2];           // per-wave free counts (greedy init)
    __shared__ int    sPred[T_];          // target t -> matched query
    __shared__ float2 sMvq[2][NWV];       // per-wave pop minima {val, bits(q)}
    __shared__ double sAcc[NWV];

    const float FINF = __builtin_inff();

    const float* pcb = pc  + (size_t)b * Q_ * NCLS1;
    const float* pbb = pbx + (size_t)b * Q_ * 4;
    const float* tbb = tbx + (size_t)b * T_ * 4;
    const int*   tlb = tl  + (size_t)b * T_;

    // ---- stage inputs + f32 softmax (same op order as jax.nn.softmax) ----
    for (int q = tid; q < Q_; q += NTH) {
        float x[NCLS1];
#pragma unroll
        for (int c = 0; c < NCLS1; ++c) x[c] = pcb[q * NCLS1 + c];
        float mx = x[0];
#pragma unroll
        for (int c = 1; c < NCLS1; ++c) mx = fmaxf(mx, x[c]);
        float ex[NCLS1];
        float sum = 0.f;
#pragma unroll
        for (int c = 0; c < NCLS1; ++c) { ex[c] = expf(x[c] - mx); sum += ex[c]; }
#pragma unroll
        for (int c = 0; c < NCLS; ++c) sProb[q * NCLS + c] = ex[c] / sum;
        sLse[q] = mx + logf(sum);
        sPb4[q] = reinterpret_cast<const float4*>(pbb)[q];
        sP[q] = 0;
        sWay[q] = 0x7fffffff;             // minrow scratch for greedy init
    }
    for (int t = tid; t < T_; t += NTH) {
        sLab[t] = tlb[t];
        sTb4[t] = reinterpret_cast<const float4*>(tbb)[t];
    }
    __syncthreads();

    // ---- phase 1: row minima u[r] = min_j cost[r][j] + argmin column.
    // 4 threads per row, 225 cols each; xor(1)+xor(2) combine with the same
    // value-then-smallest-q tie-break => identical (u, argmin) as serial. ----
    {
        const int r  = tid >> 2;          // 0..127
        const int qt = tid & 3;
        const float4 t4  = sTb4[r];
        const int    lab = sLab[r];
        float bv = FINF;
        int   bj = Q_;
        const int q0 = qt * (Q_ / 4);
        for (int q = q0; q < q0 + (Q_ / 4); ++q) {
            const float c = costQ(sPb4[q], t4, sProb[q * NCLS + lab]);
            if (c < bv) { bv = c; bj = q; }
        }
#pragma unroll
        for (int d = 1; d <= 2; d <<= 1) {
            const float ov = __shfl_xor(bv, d);
            const int   oj = __shfl_xor(bj, d);
            if (ov < bv || (ov == bv && oj < bj)) { bv = ov; bj = oj; }
        }
        if (qt == 0) { sU[r] = bv; sAmin[r] = bj; }
    }
    __syncthreads();

    // ---- greedy zero-reduced-cost assignment (parallel, serial-equivalent;
    // verified exact R16/R19/R20): row r wins col sAmin[r] iff r is the min
    // proposing row. Free list in increasing r via ballot prefix. ----
    bool isfree = false; int fpos = 0;
    if (tid < T_) atomicMin(&sWay[sAmin[tid]], tid);
    __syncthreads();
    if (tid < T_) {
        const int j = sAmin[tid];
        isfree = (sWay[j] != tid);
        if (!isfree) sP[j] = tid + 1;
        const unsigned long long bal = __ballot(isfree);
        const int lane = tid & 63;
        fpos = __popcll(bal & ((1ull << (unsigned)lane) - 1ull));
        if (lane == 0) sWcnt[tid >> 6] = (int)__popcll(bal);
    }
    __syncthreads();
    if (tid < T_ && isfree) {
        const int off = (tid >> 6) ? sWcnt[0] : 0;
        sFree[off + fpos] = tid;
    }
    if (tid == 0) sNF = sWcnt[0] + sWcnt[1];
    __syncthreads();

    // ============ block-wide deferred-dual SSP (all 8 waves scan) ============
    {
        const int lane = tid & 63;
        const int wv   = tid >> 6;
        unsigned validMask = 0;
#pragma unroll
        for (int k = 0; k < NKW; ++k)
            if (tid + (k << 9) < Q_) validMask |= 1u << k;

        float4 pbq[NKW];                  // owned predicted boxes
        float  v[NKW];                    // owned column duals
#pragma unroll
        for (int k = 0; k < NKW; ++k) {
            const int q = tid + (k << 9);
            pbq[k] = (q < Q_) ? sPb4[q] : make_float4(0.f, 0.f, 0.f, 0.f);
            v[k] = 0.f;
        }
        const int nf = sNF;

        for (int fi = 0; fi < nf; ++fi) {
            const int rf = sFree[fi];
            float minv[NKW];
            int   way[NKW];
#pragma unroll
            for (int k = 0; k < NKW; ++k) { minv[k] = FINF; way[k] = -1; }
            unsigned usedM   = ~validMask & ((1u << NKW) - 1u);
            unsigned poppedM = 0;
            int   i0row = rf;
            float dcur  = 0.f;
            int   jprev = -1;             // root marker
            float dT = 0.f; int jT = -1;
            int   buf = 0;

            for (int it = 0; it < 200; ++it) {
                const float  u0   = sU[i0row];
                const float4 t4   = sTb4[i0row];
                const int    lab  = sLab[i0row];
                const float  base = dcur - u0;

                float bestv = FINF;
                int   bestq = 1 << 29;
#pragma unroll
                for (int k = 0; k < NKW; ++k) {
                    if (!((usedM >> k) & 1u)) {
                        const int   q    = tid + (k << 9);
                        const float cost = costQ(pbq[k], t4, sProb[q * NCLS + lab]);
                        const float cur  = base + (cost - v[k]);   // R6 association
                        if (cur < minv[k]) { minv[k] = cur; way[k] = jprev; }
                        if (minv[k] < bestv) { bestv = minv[k]; bestq = q; }
                    }
                }
                // per-wave min: DPP value-min + ballot fast path; ties ->
                // exact i32 DPP min (smallest column within the wave).
                const float wval = waveMinF32(bestv);
                const unsigned long long tm = __ballot(bestv == wval);
                int wq;
                if (__popcll(tm) == 1) {
                    wq = __builtin_amdgcn_readlane(bestq, (int)__builtin_ctzll(tm));
                } else {
                    const int cand = (bestv == wval) ? bestq : 0x7fffffff;
                    wq = waveMinI32(cand);
                }
                if (lane == 0) sMvq[buf][wv] = make_float2(wval, __int_as_float(wq));
                __syncthreads();
                // global winner, computed redundantly+uniformly by all:
                // min value, smallest column on value ties (np.argmin).
                float gv = FINF; int gq = 0x7fffffff;
#pragma unroll
                for (int w = 0; w < NWV; ++w) {
                    const float2 s = sMvq[buf][w];
                    const float vw = s.x;
                    const int   qw = __float_as_int(s.y);
                    if (vw < gv)                  { gv = vw; gq = qw; }
                    else if (vw == gv && qw < gq)   gq = qw;
                }
                const float winv = gv;
                const int   winq = gq;

                if (tid == (winq & (NTH - 1))) usedM |= 1u << (winq >> 9);  // freeze
                const int rowm = sP[winq];      // broadcast read, uniform
                if (rowm == 0) { dT = winv; jT = winq; break; }   // free col: done
                if (tid == (winq & (NTH - 1))) poppedM |= 1u << (winq >> 9);
                jprev = winq; i0row = rowm - 1; dcur = winv; buf ^= 1;
            }

            // flush way regs (augment only reads cols improved this pass)
#pragma unroll
            for (int k = 0; k < NKW; ++k) {
                if ((validMask >> k) & 1u) sWay[tid + (k << 9)] = way[k];
            }
            // deferred dual updates (== e-maxx incremental totals), pre-augment;
            // popped columns have distinct assigned rows -> race-free.
#pragma unroll
            for (int k = 0; k < NKW; ++k) {
                if ((poppedM >> k) & 1u) {
                    const int q   = tid + (k << 9);
                    const int row = sP[q] - 1;
                    sU[row] += dT - minv[k];
                    v[k]    += minv[k] - dT;
                }
            }
            if (tid == 0) sU[rf] += dT;
            __syncthreads();
            if (tid == 0 && jT >= 0) {                // augment along parents
                int jj = jT, guard = 0;
                while (guard++ < 200) {
                    const int jp = sWay[jj];
                    if (jp < 0) { sP[jj] = rf + 1; break; }
                    sP[jj] = sP[jp];
                    jj = jp;
                }
            }
            __syncthreads();
        }
    }
    __syncthreads();

    // ---- extract matching: pred query for each target ----
    for (int q = tid; q < Q_; q += NTH) {
        const int pi = sP[q];
        if (pi > 0) sPred[pi - 1] = q;
    }
    __syncthreads();

    // ---- tc[] (reuse sWay): NUM_CLASSES default, matched queries get label ----
    int* sTc = sWay;
    for (int q = tid; q < Q_; q += NTH) sTc[q] = NCLS;
    __syncthreads();
    for (int t = tid; t < T_; t += NTH) sTc[sPred[t]] = sLab[t];  // sPred distinct
    __syncthreads();

    // ---- weighted CE over all queries ----
    double swn = 0.0, sw = 0.0;
    for (int q = tid; q < Q_; q += NTH) {
        const int   c   = sTc[q];
        const float xv  = pcb[q * NCLS1 + c];
        const float nll = sLse[q] - xv;              // -log_softmax[tc]
        const double w  = (c == NCLS) ? (double)0.05f : 1.0;
        swn += w * (double)nll;
        sw  += w;
    }

    // ---- bbox L1 + GIoU over matched pairs ----
    double l1s = 0.0, gs = 0.0;
    for (int t = tid; t < T_; t += NTH) {
        const int q = sPred[t];
        const float4 p4 = sPb4[q];
        const float4 t4 = sTb4[t];
        l1s += (double)fabsf(p4.x - t4.x) + (double)fabsf(p4.y - t4.y)
             + (double)fabsf(p4.z - t4.z) + (double)fabsf(p4.w - t4.w);
        const float ax1 = p4.x - 0.5f * p4.z, ay1 = p4.y - 0.5f * p4.w;
        const float ax2 = p4.x + 0.5f * p4.z, ay2 = p4.y + 0.5f * p4.w;
        const float bx1 = t4.x - 0.5f * t4.z, by1 = t4.y - 0.5f * t4.w;
        const float bx2 = t4.x + 0.5f * t4.z, by2 = t4.y + 0.5f * t4.w;
        const double a1 = (double)(ax2 - ax1) * (double)(ay2 - ay1);
        const double a2 = (double)(bx2 - bx1) * (double)(by2 - by1);
        const double ltx = fmax((double)ax1, (double)bx1);
        const double lty = fmax((double)ay1, (double)by1);
        const double rbx = fmin((double)ax2, (double)bx2);
        const double rby = fmin((double)ay2, (double)by2);
        const double iw = fmax(rbx - ltx, 0.0), ih = fmax(rby - lty, 0.0);
        const double inter = iw * ih;
        const double uni   = a1 + a2 - inter;
        const double iou   = inter / uni;
        const double cx1 = fmin((double)ax1, (double)bx1);
        const double cy1 = fmin((double)ay1, (double)by1);
        const double cx2 = fmax((double)ax2, (double)bx2);
        const double cy2 = fmax((double)ay2, (double)by2);
        const double ac  = (cx2 - cx1) * (cy2 - cy1);
        const double giou = iou - (ac - uni) / ac;
        gs += 1.0 - giou;
    }

    const double swnT = blockSum(swn, sAcc, tid);
    const double swT  = blockSum(sw,  sAcc, tid);
    const double l1T  = blockSum(l1s, sAcc, tid);
    const double gsT  = blockSum(gs,  sAcc, tid);
    if (tid == 0) {
        const double cls = swnT / swT;
        const double bb  = 5.0 * (l1T / (double)(T_ * 4)) + 2.0 * (gsT / (double)T_);
        const double mine = (cls + bb) / 8192.0;
        // fused finalize: CAS converts the 0xAA poison to 0.0 exactly once
        // (each block CASes before its own add; no spin), then atomic f32 sum.
        atomicCAS((unsigned int*)out, 0xAAAAAAAAu, 0u);
        atomicAdd(out, (float)mine);
    }
}

extern "C" void kernel_launch(void* const* d_in, const int* in_sizes, int n_in,
                              void* d_out, int out_size, void* d_ws, size_t ws_size,
                              hipStream_t stream) {
    const float* pc  = (const float*)d_in[0];   // predicted_class [64,900,14]
    const float* pbx = (const float*)d_in[1];   // predicted_bbox  [64,900,4]
    const int*   tl  = (const int*)  d_in[2];   // target_labels   [64,128]
    const float* tbx = (const float*)d_in[3];   // target_boxes    [64,128,4]
    (void)in_sizes; (void)n_in; (void)out_size; (void)d_ws; (void)ws_size;

    detr_hungarian_loss<<<dim3(B_), dim3(NTH), 0, stream>>>(pc, pbx, tl, tbx,
                                                            (float*)d_out);
}

// Round 10
// 107.978 us; speedup vs baseline: 1.2572x; 1.0532x over previous
//
#include <hip/hip_runtime.h>
#include <math.h>

// Problem constants (from reference): B=64, Q=900, T=128, NUM_CLASSES=13
#define B_    64
#define Q_    900
#define T_    128
#define NCLS  13
#define NCLS1 14
#define NTH   512
#define NWV   (NTH / 64)
#define NKW   2           // block-wide scan: col q = tid + 512*k, k<NKW

// Block-wide f64 sum; result valid on tid 0. All threads must call.
__device__ __forceinline__ double blockSum(double v, double* sAcc, int tid) {
#pragma unroll
    for (int off = 32; off > 0; off >>= 1) v += __shfl_down(v, off);
    if ((tid & 63) == 0) sAcc[tid >> 6] = v;
    __syncthreads();
    if (tid == 0) {
#pragma unroll
        for (int w = 1; w < NWV; ++w) v += sAcc[w];
    }
    __syncthreads();
    return v;
}

// f32 cost entry, identical op order to the jnp reference:
// (|dx|+|dy|+|dz|+|dw| summed left-to-right) - prob[lab].
__device__ __forceinline__ float costQ(const float4 p4, const float4 t4, const float pr) {
    float cb = fabsf(p4.x - t4.x);
    cb = cb + fabsf(p4.y - t4.y);
    cb = cb + fabsf(p4.z - t4.z);
    cb = cb + fabsf(p4.w - t4.w);
    return cb - pr;
}

// ---- DPP full-wave min reductions (row_shr + row_bcast chain) ----
// Verified exact on R11/R13/R16/R20/R23 (absmax 0). Uniform via readlane(63).
#define DPP_ROW_SHR1 0x111
#define DPP_ROW_SHR2 0x112
#define DPP_ROW_SHR4 0x114
#define DPP_ROW_SHR8 0x118
#define DPP_BCAST15  0x142
#define DPP_BCAST31  0x143

__device__ __forceinline__ float waveMinF32(float x) {
    const int INFI = 0x7f800000;                       // +inf bits
    float f = x;
#define MRED(C) { const int o = __builtin_amdgcn_update_dpp(INFI, __float_as_int(f), C, 0xf, 0xf, false); \
                  f = fminf(f, __int_as_float(o)); }
    MRED(DPP_ROW_SHR1) MRED(DPP_ROW_SHR2) MRED(DPP_ROW_SHR4) MRED(DPP_ROW_SHR8)
    MRED(DPP_BCAST15)  MRED(DPP_BCAST31)
#undef MRED
    return __int_as_float(__builtin_amdgcn_readlane(__float_as_int(f), 63));
}

__device__ __forceinline__ int waveMinI32(int x) {
    int f = x;
#define MRED(C) { const int o = __builtin_amdgcn_update_dpp(0x7fffffff, f, C, 0xf, 0xf, false); \
                  f = (o < f) ? o : f; }
    MRED(DPP_ROW_SHR1) MRED(DPP_ROW_SHR2) MRED(DPP_ROW_SHR4) MRED(DPP_ROW_SHR8)
    MRED(DPP_BCAST15)  MRED(DPP_BCAST31)
#undef MRED
    return __builtin_amdgcn_readlane(f, 63);
}

// One block per image. History: R16/R19 94us; R20 69.4us; R23 8-wave 58.4us
// (absmax 0) = baseline. REVERTED: R17 (trajectory), R18/R21/R22 (pop-chain
// additions regress). Lesson: only REMOVE post-barrier work.
// This round (R24): packed-u64 winner selection. Per-wave lane0 packs
// (monotone-key(value) << 32 | q) and LDS-atomicMin's into one slot;
// post-barrier select becomes ONE broadcast ds_read_b64 + unpack instead of
// 8 slot reads + 21-op compare chain. u64 lexicographic min == (min value,
// then smallest q) == previous selection semantics exactly; the ±0.0 key
// special-case preserves float-equality ties. 4-slot round-robin re-arm
// ((it+2)&3 pre-barrier) keeps every re-arm barrier-separated from both the
// readers and the next atomics to that slot. Values bit-identical => same
// trajectory, absmax 0.
extern "C" __global__ __launch_bounds__(NTH, 1)
void detr_hungarian_loss(const float* __restrict__ pc,    // [B,Q,14]
                         const float* __restrict__ pbx,   // [B,Q,4]
                         const int*   __restrict__ tl,    // [B,T]
                         const float* __restrict__ tbx,   // [B,T,4]
                         float* __restrict__ out)         // [1], poisoned 0xAA
{
    const int b   = blockIdx.x;
    const int tid = threadIdx.x;

    __shared__ float  sProb[Q_ * NCLS];   // softmax probs, classes 0..12
    __shared__ float  sLse[Q_];           // logsumexp per query (for CE)
    __shared__ float4 sPb4[Q_];           // predicted boxes
    __shared__ float4 sTb4[T_];           // target boxes
    __shared__ int    sLab[T_];           // target labels
    __shared__ float  sU[T_];             // row duals (f32)
    __shared__ int    sP[Q_];             // col -> row+1, 0 = free
    __shared__ int    sWay[Q_];           // parent cols (per pass); scratch: minrow; reused as tc[]
    __shared__ int    sAmin[T_];          // row -> argmin column
    __shared__ int    sFree[T_];
    __shared__ int    sNF;
    __shared__ int    sWcnt[2];           // per-wave free counts (greedy init)
    __shared__ int    sPred[T_];          // target t -> matched query
    __shared__ unsigned long long sSlot[4]; // packed pop minima, round-robin
    __shared__ double sAcc[NWV];

    const float FINF = __builtin_inff();

    const float* pcb = pc  + (size_t)b * Q_ * NCLS1;
    const float* pbb = pbx + (size_t)b * Q_ * 4;
    const float* tbb = tbx + (size_t)b * T_ * 4;
    const int*   tlb = tl  + (size_t)b * T_;

    // ---- stage inputs + f32 softmax (same op order as jax.nn.softmax) ----
    for (int q = tid; q < Q_; q += NTH) {
        float x[NCLS1];
#pragma unroll
        for (int c = 0; c < NCLS1; ++c) x[c] = pcb[q * NCLS1 + c];
        float mx = x[0];
#pragma unroll
        for (int c = 1; c < NCLS1; ++c) mx = fmaxf(mx, x[c]);
        float ex[NCLS1];
        float sum = 0.f;
#pragma unroll
        for (int c = 0; c < NCLS1; ++c) { ex[c] = expf(x[c] - mx); sum += ex[c]; }
#pragma unroll
        for (int c = 0; c < NCLS; ++c) sProb[q * NCLS + c] = ex[c] / sum;
        sLse[q] = mx + logf(sum);
        sPb4[q] = reinterpret_cast<const float4*>(pbb)[q];
        sP[q] = 0;
        sWay[q] = 0x7fffffff;             // minrow scratch for greedy init
    }
    for (int t = tid; t < T_; t += NTH) {
        sLab[t] = tlb[t];
        sTb4[t] = reinterpret_cast<const float4*>(tbb)[t];
    }
    __syncthreads();

    // ---- phase 1: row minima u[r] = min_j cost[r][j] + argmin column.
    // 4 threads per row, 225 cols each; xor(1)+xor(2) combine with the same
    // value-then-smallest-q tie-break => identical (u, argmin) as serial. ----
    {
        const int r  = tid >> 2;          // 0..127
        const int qt = tid & 3;
        const float4 t4  = sTb4[r];
        const int    lab = sLab[r];
        float bv = FINF;
        int   bj = Q_;
        const int q0 = qt * (Q_ / 4);
        for (int q = q0; q < q0 + (Q_ / 4); ++q) {
            const float c = costQ(sPb4[q], t4, sProb[q * NCLS + lab]);
            if (c < bv) { bv = c; bj = q; }
        }
#pragma unroll
        for (int d = 1; d <= 2; d <<= 1) {
            const float ov = __shfl_xor(bv, d);
            const int   oj = __shfl_xor(bj, d);
            if (ov < bv || (ov == bv && oj < bj)) { bv = ov; bj = oj; }
        }
        if (qt == 0) { sU[r] = bv; sAmin[r] = bj; }
    }
    __syncthreads();

    // ---- greedy zero-reduced-cost assignment (parallel, serial-equivalent;
    // verified exact R16/R19/R20/R23): row r wins col sAmin[r] iff r is the
    // min proposing row. Free list in increasing r via ballot prefix. ----
    bool isfree = false; int fpos = 0;
    if (tid < T_) atomicMin(&sWay[sAmin[tid]], tid);
    __syncthreads();
    if (tid < T_) {
        const int j = sAmin[tid];
        isfree = (sWay[j] != tid);
        if (!isfree) sP[j] = tid + 1;
        const unsigned long long bal = __ballot(isfree);
        const int lane = tid & 63;
        fpos = __popcll(bal & ((1ull << (unsigned)lane) - 1ull));
        if (lane == 0) sWcnt[tid >> 6] = (int)__popcll(bal);
    }
    __syncthreads();
    if (tid < T_ && isfree) {
        const int off = (tid >> 6) ? sWcnt[0] : 0;
        sFree[off + fpos] = tid;
    }
    if (tid == 0) sNF = sWcnt[0] + sWcnt[1];
    __syncthreads();

    // ============ block-wide deferred-dual SSP (all 8 waves scan) ============
    {
        const int lane = tid & 63;
        unsigned validMask = 0;
#pragma unroll
        for (int k = 0; k < NKW; ++k)
            if (tid + (k << 9) < Q_) validMask |= 1u << k;

        float4 pbq[NKW];                  // owned predicted boxes
        float  v[NKW];                    // owned column duals
#pragma unroll
        for (int k = 0; k < NKW; ++k) {
            const int q = tid + (k << 9);
            pbq[k] = (q < Q_) ? sPb4[q] : make_float4(0.f, 0.f, 0.f, 0.f);
            v[k] = 0.f;
        }
        const int nf = sNF;

        for (int fi = 0; fi < nf; ++fi) {
            const int rf = sFree[fi];
            float minv[NKW];
            int   way[NKW];
#pragma unroll
            for (int k = 0; k < NKW; ++k) { minv[k] = FINF; way[k] = -1; }
            unsigned usedM   = ~validMask & ((1u << NKW) - 1u);
            unsigned poppedM = 0;
            int   i0row = rf;
            float dcur  = 0.f;
            int   jprev = -1;             // root marker
            float dT = 0.f; int jT = -1;

            if (tid < 4) sSlot[tid] = ~0ull;   // arm all 4 slots
            __syncthreads();

            for (int it = 0; it < 200; ++it) {
                const int    buf  = it & 3;
                const float  u0   = sU[i0row];
                const float4 t4   = sTb4[i0row];
                const int    lab  = sLab[i0row];
                const float  base = dcur - u0;

                float bestv = FINF;
                int   bestq = 1 << 29;
#pragma unroll
                for (int k = 0; k < NKW; ++k) {
                    if (!((usedM >> k) & 1u)) {
                        const int   q    = tid + (k << 9);
                        const float cost = costQ(pbq[k], t4, sProb[q * NCLS + lab]);
                        const float cur  = base + (cost - v[k]);   // R6 association
                        if (cur < minv[k]) { minv[k] = cur; way[k] = jprev; }
                        if (minv[k] < bestv) { bestv = minv[k]; bestq = q; }
                    }
                }
                // per-wave min: DPP value-min + ballot fast path; ties ->
                // exact i32 DPP min (smallest column within the wave).
                const float wval = waveMinF32(bestv);
                const unsigned long long tm = __ballot(bestv == wval);
                int wq;
                if (__popcll(tm) == 1) {
                    wq = __builtin_amdgcn_readlane(bestq, (int)__builtin_ctzll(tm));
                } else {
                    const int cand = (bestv == wval) ? bestq : 0x7fffffff;
                    wq = waveMinI32(cand);
                }
                if (lane == 0) {
                    // monotone f32->u32 key; +-0.0 share one key so float-
                    // equality ties still resolve to the smallest column.
                    const unsigned s = __float_as_uint(wval);
                    const unsigned key = (s == 0x80000000u) ? 0x80000000u
                                       : ((s & 0x80000000u) ? ~s : (s | 0x80000000u));
                    atomicMin(&sSlot[buf],
                              ((unsigned long long)key << 32) |
                               (unsigned long long)(unsigned)wq);
                }
                if (tid == 0) sSlot[(it + 2) & 3] = ~0ull;  // re-arm (safe slot)
                __syncthreads();
                // global winner: ONE broadcast read, u64 min == (min value,
                // smallest q) lexicographic == np.argmin semantics.
                const unsigned long long m = sSlot[buf];
                const unsigned kk   = (unsigned)(m >> 32);
                const int      winq = (int)(m & 0xffffffffull);
                const float    winv = __uint_as_float(
                    (kk & 0x80000000u) ? (kk ^ 0x80000000u) : ~kk);

                if (tid == (winq & (NTH - 1))) usedM |= 1u << (winq >> 9);  // freeze
                const int rowm = sP[winq];      // broadcast read, uniform
                if (rowm == 0) { dT = winv; jT = winq; break; }   // free col: done
                if (tid == (winq & (NTH - 1))) poppedM |= 1u << (winq >> 9);
                jprev = winq; i0row = rowm - 1; dcur = winv;
            }

            // flush way regs (augment only reads cols improved this pass)
#pragma unroll
            for (int k = 0; k < NKW; ++k) {
                if ((validMask >> k) & 1u) sWay[tid + (k << 9)] = way[k];
            }
            // deferred dual updates (== e-maxx incremental totals), pre-augment;
            // popped columns have distinct assigned rows -> race-free.
#pragma unroll
            for (int k = 0; k < NKW; ++k) {
                if ((poppedM >> k) & 1u) {
                    const int q   = tid + (k << 9);
                    const int row = sP[q] - 1;
                    sU[row] += dT - minv[k];
                    v[k]    += minv[k] - dT;
                }
            }
            if (tid == 0) sU[rf] += dT;
            __syncthreads();
            if (tid == 0 && jT >= 0) {                // augment along parents
                int jj = jT, guard = 0;
                while (guard++ < 200) {
                    const int jp = sWay[jj];
                    if (jp < 0) { sP[jj] = rf + 1; break; }
                    sP[jj] = sP[jp];
                    jj = jp;
                }
            }
            __syncthreads();
        }
    }
    __syncthreads();

    // ---- extract matching: pred query for each target ----
    for (int q = tid; q < Q_; q += NTH) {
        const int pi = sP[q];
        if (pi > 0) sPred[pi - 1] = q;
    }
    __syncthreads();

    // ---- tc[] (reuse sWay): NUM_CLASSES default, matched queries get label ----
    int* sTc = sWay;
    for (int q = tid; q < Q_; q += NTH) sTc[q] = NCLS;
    __syncthreads();
    for (int t = tid; t < T_; t += NTH) sTc[sPred[t]] = sLab[t];  // sPred distinct
    __syncthreads();

    // ---- weighted CE over all queries ----
    double swn = 0.0, sw = 0.0;
    for (int q = tid; q < Q_; q += NTH) {
        const int   c   = sTc[q];
        const float xv  = pcb[q * NCLS1 + c];
        const float nll = sLse[q] - xv;              // -log_softmax[tc]
        const double w  = (c == NCLS) ? (double)0.05f : 1.0;
        swn += w * (double)nll;
        sw  += w;
    }

    // ---- bbox L1 + GIoU over matched pairs ----
    double l1s = 0.0, gs = 0.0;
    for (int t = tid; t < T_; t += NTH) {
        const int q = sPred[t];
        const float4 p4 = sPb4[q];
        const float4 t4 = sTb4[t];
        l1s += (double)fabsf(p4.x - t4.x) + (double)fabsf(p4.y - t4.y)
             + (double)fabsf(p4.z - t4.z) + (double)fabsf(p4.w - t4.w);
        const float ax1 = p4.x - 0.5f * p4.z, ay1 = p4.y - 0.5f * p4.w;
        const float ax2 = p4.x + 0.5f * p4.z, ay2 = p4.y + 0.5f * p4.w;
        const float bx1 = t4.x - 0.5f * t4.z, by1 = t4.y - 0.5f * t4.w;
        const float bx2 = t4.x + 0.5f * t4.z, by2 = t4.y + 0.5f * t4.w;
        const double a1 = (double)(ax2 - ax1) * (double)(ay2 - ay1);
        const double a2 = (double)(bx2 - bx1) * (double)(by2 - by1);
        const double ltx = fmax((double)ax1, (double)bx1);
        const double lty = fmax((double)ay1, (double)by1);
        const double rbx = fmin((double)ax2, (double)bx2);
        const double rby = fmin((double)ay2, (double)by2);
        const double iw = fmax(rbx - ltx, 0.0), ih = fmax(rby - lty, 0.0);
        const double inter = iw * ih;
        const double uni   = a1 + a2 - inter;
        const double iou   = inter / uni;
        const double cx1 = fmin((double)ax1, (double)bx1);
        const double cy1 = fmin((double)ay1, (double)by1);
        const double cx2 = fmax((double)ax2, (double)bx2);
        const double cy2 = fmax((double)ay2, (double)by2);
        const double ac  = (cx2 - cx1) * (cy2 - cy1);
        const double giou = iou - (ac - uni) / ac;
        gs += 1.0 - giou;
    }

    const double swnT = blockSum(swn, sAcc, tid);
    const double swT  = blockSum(sw,  sAcc, tid);
    const double l1T  = blockSum(l1s, sAcc, tid);
    const double gsT  = blockSum(gs,  sAcc, tid);
    if (tid == 0) {
        const double cls = swnT / swT;
        const double bb  = 5.0 * (l1T / (double)(T_ * 4)) + 2.0 * (gsT / (double)T_);
        const double mine = (cls + bb) / 8192.0;
        // fused finalize: CAS converts the 0xAA poison to 0.0 exactly once
        // (each block CASes before its own add; no spin), then atomic f32 sum.
        atomicCAS((unsigned int*)out, 0xAAAAAAAAu, 0u);
        atomicAdd(out, (float)mine);
    }
}

extern "C" void kernel_launch(void* const* d_in, const int* in_sizes, int n_in,
                              void* d_out, int out_size, void* d_ws, size_t ws_size,
                              hipStream_t stream) {
    const float* pc  = (const float*)d_in[0];   // predicted_class [64,900,14]
    const float* pbx = (const float*)d_in[1];   // predicted_bbox  [64,900,4]
    const int*   tl  = (const int*)  d_in[2];   // target_labels   [64,128]
    const float* tbx = (const float*)d_in[3];   // target_boxes    [64,128,4]
    (void)in_sizes; (void)n_in; (void)out_size; (void)d_ws; (void)ws_size;

    detr_hungarian_loss<<<dim3(B_), dim3(NTH), 0, stream>>>(pc, pbx, tl, tbx,
                                                            (float*)d_out);
}

// Round 11
// 107.876 us; speedup vs baseline: 1.2584x; 1.0009x over previous
//
#include <hip/hip_runtime.h>
#include <math.h>

// Problem constants (from reference): B=64, Q=900, T=128, NUM_CLASSES=13
#define B_    64
#define Q_    900
#define T_    128
#define NCLS  13
#define NCLS1 14
#define NTH   512
#define NWV   (NTH / 64)
#define NKW   2           // block-wide scan: col q = tid + 512*k, k<NKW

// Block-wide f64 sum; result valid on tid 0. All threads must call.
__device__ __forceinline__ double blockSum(double v, double* sAcc, int tid) {
#pragma unroll
    for (int off = 32; off > 0; off >>= 1) v += __shfl_down(v, off);
    if ((tid & 63) == 0) sAcc[tid >> 6] = v;
    __syncthreads();
    if (tid == 0) {
#pragma unroll
        for (int w = 1; w < NWV; ++w) v += sAcc[w];
    }
    __syncthreads();
    return v;
}

// f32 cost entry, identical op order to the jnp reference:
// (|dx|+|dy|+|dz|+|dw| summed left-to-right) - prob[lab].
__device__ __forceinline__ float costQ(const float4 p4, const float4 t4, const float pr) {
    float cb = fabsf(p4.x - t4.x);
    cb = cb + fabsf(p4.y - t4.y);
    cb = cb + fabsf(p4.z - t4.z);
    cb = cb + fabsf(p4.w - t4.w);
    return cb - pr;
}

// ---- DPP full-wave min reductions (row_shr + row_bcast chain) ----
// Verified exact on R11/R13/R16/R20/R23/R24 (absmax 0). Uniform via readlane(63).
#define DPP_ROW_SHR1 0x111
#define DPP_ROW_SHR2 0x112
#define DPP_ROW_SHR4 0x114
#define DPP_ROW_SHR8 0x118
#define DPP_BCAST15  0x142
#define DPP_BCAST31  0x143

__device__ __forceinline__ float waveMinF32(float x) {
    const int INFI = 0x7f800000;                       // +inf bits
    float f = x;
#define MRED(C) { const int o = __builtin_amdgcn_update_dpp(INFI, __float_as_int(f), C, 0xf, 0xf, false); \
                  f = fminf(f, __int_as_float(o)); }
    MRED(DPP_ROW_SHR1) MRED(DPP_ROW_SHR2) MRED(DPP_ROW_SHR4) MRED(DPP_ROW_SHR8)
    MRED(DPP_BCAST15)  MRED(DPP_BCAST31)
#undef MRED
    return __int_as_float(__builtin_amdgcn_readlane(__float_as_int(f), 63));
}

__device__ __forceinline__ int waveMinI32(int x) {
    int f = x;
#define MRED(C) { const int o = __builtin_amdgcn_update_dpp(0x7fffffff, f, C, 0xf, 0xf, false); \
                  f = (o < f) ? o : f; }
    MRED(DPP_ROW_SHR1) MRED(DPP_ROW_SHR2) MRED(DPP_ROW_SHR4) MRED(DPP_ROW_SHR8)
    MRED(DPP_BCAST15)  MRED(DPP_BCAST31)
#undef MRED
    return __builtin_amdgcn_readlane(f, 63);
}

// One block per image. History: R16/R19 94us; R20 69.4us; R23 58.4us; R24
// packed-u64 select 51.6us (absmax 0) = baseline. REVERTED: R17
// (trajectory), R18/R21/R22 (pop-chain ADDITIONS regress; only REMOVING
// post-barrier work wins).
// This round (R25): rowm rides the packed slot. After the scan, each lane
// issues sP[bestq] for its OWN best column (64 parallel reads; latency hides
// under the DPP reduce), the winning lane's rowm travels via readlane and is
// packed as [key:32][q:24][rowm:8] into the atomicMin slot. (key,q) ties =>
// same column => same rowm, so lexicographic-min semantics are unchanged;
// the all-frozen +inf entry's key (>=0xFF800000) strictly exceeds any finite
// key (<=0xFF7FFFFF) so its q-field garbage never wins. Post-barrier chain
// loses the dependent sP[winq] read entirely. sP constant during pop loop =>
// bit-identical values => same trajectory, absmax 0.
extern "C" __global__ __launch_bounds__(NTH, 1)
void detr_hungarian_loss(const float* __restrict__ pc,    // [B,Q,14]
                         const float* __restrict__ pbx,   // [B,Q,4]
                         const int*   __restrict__ tl,    // [B,T]
                         const float* __restrict__ tbx,   // [B,T,4]
                         float* __restrict__ out)         // [1], poisoned 0xAA
{
    const int b   = blockIdx.x;
    const int tid = threadIdx.x;

    __shared__ float  sProb[Q_ * NCLS];   // softmax probs, classes 0..12
    __shared__ float  sLse[Q_];           // logsumexp per query (for CE)
    __shared__ float4 sPb4[Q_];           // predicted boxes
    __shared__ float4 sTb4[T_];           // target boxes
    __shared__ int    sLab[T_];           // target labels
    __shared__ float  sU[T_];             // row duals (f32)
    __shared__ int    sP[Q_];             // col -> row+1, 0 = free
    __shared__ int    sWay[Q_];           // parent cols (per pass); scratch: minrow; reused as tc[]
    __shared__ int    sAmin[T_];          // row -> argmin column
    __shared__ int    sFree[T_];
    __shared__ int    sNF;
    __shared__ int    sWcnt[2];           // per-wave free counts (greedy init)
    __shared__ int    sPred[T_];          // target t -> matched query
    __shared__ unsigned long long sSlot[4]; // packed pop minima, round-robin
    __shared__ double sAcc[NWV];

    const float FINF = __builtin_inff();

    const float* pcb = pc  + (size_t)b * Q_ * NCLS1;
    const float* pbb = pbx + (size_t)b * Q_ * 4;
    const float* tbb = tbx + (size_t)b * T_ * 4;
    const int*   tlb = tl  + (size_t)b * T_;

    // ---- stage inputs + f32 softmax (same op order as jax.nn.softmax) ----
    for (int q = tid; q < Q_; q += NTH) {
        float x[NCLS1];
#pragma unroll
        for (int c = 0; c < NCLS1; ++c) x[c] = pcb[q * NCLS1 + c];
        float mx = x[0];
#pragma unroll
        for (int c = 1; c < NCLS1; ++c) mx = fmaxf(mx, x[c]);
        float ex[NCLS1];
        float sum = 0.f;
#pragma unroll
        for (int c = 0; c < NCLS1; ++c) { ex[c] = expf(x[c] - mx); sum += ex[c]; }
#pragma unroll
        for (int c = 0; c < NCLS; ++c) sProb[q * NCLS + c] = ex[c] / sum;
        sLse[q] = mx + logf(sum);
        sPb4[q] = reinterpret_cast<const float4*>(pbb)[q];
        sP[q] = 0;
        sWay[q] = 0x7fffffff;             // minrow scratch for greedy init
    }
    for (int t = tid; t < T_; t += NTH) {
        sLab[t] = tlb[t];
        sTb4[t] = reinterpret_cast<const float4*>(tbb)[t];
    }
    __syncthreads();

    // ---- phase 1: row minima u[r] = min_j cost[r][j] + argmin column.
    // 4 threads per row, 225 cols each; xor(1)+xor(2) combine with the same
    // value-then-smallest-q tie-break => identical (u, argmin) as serial. ----
    {
        const int r  = tid >> 2;          // 0..127
        const int qt = tid & 3;
        const float4 t4  = sTb4[r];
        const int    lab = sLab[r];
        float bv = FINF;
        int   bj = Q_;
        const int q0 = qt * (Q_ / 4);
        for (int q = q0; q < q0 + (Q_ / 4); ++q) {
            const float c = costQ(sPb4[q], t4, sProb[q * NCLS + lab]);
            if (c < bv) { bv = c; bj = q; }
        }
#pragma unroll
        for (int d = 1; d <= 2; d <<= 1) {
            const float ov = __shfl_xor(bv, d);
            const int   oj = __shfl_xor(bj, d);
            if (ov < bv || (ov == bv && oj < bj)) { bv = ov; bj = oj; }
        }
        if (qt == 0) { sU[r] = bv; sAmin[r] = bj; }
    }
    __syncthreads();

    // ---- greedy zero-reduced-cost assignment (parallel, serial-equivalent;
    // verified exact R16/R19/R20/R23/R24): row r wins col sAmin[r] iff r is
    // the min proposing row. Free list in increasing r via ballot prefix. ----
    bool isfree = false; int fpos = 0;
    if (tid < T_) atomicMin(&sWay[sAmin[tid]], tid);
    __syncthreads();
    if (tid < T_) {
        const int j = sAmin[tid];
        isfree = (sWay[j] != tid);
        if (!isfree) sP[j] = tid + 1;
        const unsigned long long bal = __ballot(isfree);
        const int lane = tid & 63;
        fpos = __popcll(bal & ((1ull << (unsigned)lane) - 1ull));
        if (lane == 0) sWcnt[tid >> 6] = (int)__popcll(bal);
    }
    __syncthreads();
    if (tid < T_ && isfree) {
        const int off = (tid >> 6) ? sWcnt[0] : 0;
        sFree[off + fpos] = tid;
    }
    if (tid == 0) sNF = sWcnt[0] + sWcnt[1];
    __syncthreads();

    // ============ block-wide deferred-dual SSP (all 8 waves scan) ============
    {
        const int lane = tid & 63;
        unsigned validMask = 0;
#pragma unroll
        for (int k = 0; k < NKW; ++k)
            if (tid + (k << 9) < Q_) validMask |= 1u << k;

        float4 pbq[NKW];                  // owned predicted boxes
        float  v[NKW];                    // owned column duals
#pragma unroll
        for (int k = 0; k < NKW; ++k) {
            const int q = tid + (k << 9);
            pbq[k] = (q < Q_) ? sPb4[q] : make_float4(0.f, 0.f, 0.f, 0.f);
            v[k] = 0.f;
        }
        const int nf = sNF;

        for (int fi = 0; fi < nf; ++fi) {
            const int rf = sFree[fi];
            float minv[NKW];
            int   way[NKW];
#pragma unroll
            for (int k = 0; k < NKW; ++k) { minv[k] = FINF; way[k] = -1; }
            unsigned usedM   = ~validMask & ((1u << NKW) - 1u);
            unsigned poppedM = 0;
            int   i0row = rf;
            float dcur  = 0.f;
            int   jprev = -1;             // root marker
            float dT = 0.f; int jT = -1;

            if (tid < 4) sSlot[tid] = ~0ull;   // arm all 4 slots
            __syncthreads();

            for (int it = 0; it < 200; ++it) {
                const int    buf  = it & 3;
                const float  u0   = sU[i0row];
                const float4 t4   = sTb4[i0row];
                const int    lab  = sLab[i0row];
                const float  base = dcur - u0;

                float bestv = FINF;
                int   bestq = 1 << 29;
#pragma unroll
                for (int k = 0; k < NKW; ++k) {
                    if (!((usedM >> k) & 1u)) {
                        const int   q    = tid + (k << 9);
                        const float cost = costQ(pbq[k], t4, sProb[q * NCLS + lab]);
                        const float cur  = base + (cost - v[k]);   // R6 association
                        if (cur < minv[k]) { minv[k] = cur; way[k] = jprev; }
                        if (minv[k] < bestv) { bestv = minv[k]; bestq = q; }
                    }
                }
                // per-lane sP prefetch of own best column: issued here so its
                // ~50cy latency hides under the DPP reduce. sP is constant
                // inside the pop loop, so values are exact.
                const int myrow = sP[((unsigned)bestq < (unsigned)Q_) ? bestq : 0];
                // per-wave min: DPP value-min + ballot fast path; ties ->
                // exact i32 DPP min (smallest column within the wave).
                const float wval = waveMinF32(bestv);
                const unsigned long long tm = __ballot(bestv == wval);
                int wq, wrow;
                if (__popcll(tm) == 1) {
                    const int wl = (int)__builtin_ctzll(tm);
                    wq   = __builtin_amdgcn_readlane(bestq, wl);
                    wrow = __builtin_amdgcn_readlane(myrow, wl);
                } else {
                    const int cand = (bestv == wval) ? bestq : 0x7fffffff;
                    wq = waveMinI32(cand);
                    const unsigned long long tw =
                        __ballot(bestv == wval && bestq == wq);
                    const int wl = (int)__builtin_ctzll(tw);
                    wrow = __builtin_amdgcn_readlane(myrow, wl);
                }
                if (lane == 0) {
                    // monotone f32->u32 key; +-0.0 share one key so float-
                    // equality ties still resolve to the smallest column.
                    const unsigned s = __float_as_uint(wval);
                    const unsigned key = (s == 0x80000000u) ? 0x80000000u
                                       : ((s & 0x80000000u) ? ~s : (s | 0x80000000u));
                    const unsigned long long pk =
                        ((unsigned long long)key << 32) |
                        ((unsigned long long)((unsigned)wq & 0xFFFFFFu) << 8) |
                        (unsigned long long)((unsigned)wrow & 0xFFu);
                    atomicMin(&sSlot[buf], pk);
                }
                if (tid == 0) sSlot[(it + 2) & 3] = ~0ull;  // re-arm (safe slot)
                __syncthreads();
                // global winner: ONE broadcast read; u64 min == (min value,
                // smallest q) lexicographic == np.argmin semantics; rowm
                // rides along (same column => same rowm on ties).
                const unsigned long long m = sSlot[buf];
                const unsigned kk   = (unsigned)(m >> 32);
                const int      winq = (int)((m >> 8) & 0xFFFFFFull);
                const int      rowm = (int)(m & 0xFFull);
                const float    winv = __uint_as_float(
                    (kk & 0x80000000u) ? (kk ^ 0x80000000u) : ~kk);

                if (tid == (winq & (NTH - 1))) usedM |= 1u << (winq >> 9);  // freeze
                if (rowm == 0) { dT = winv; jT = winq; break; }   // free col: done
                if (tid == (winq & (NTH - 1))) poppedM |= 1u << (winq >> 9);
                jprev = winq; i0row = rowm - 1; dcur = winv;
            }

            // flush way regs (augment only reads cols improved this pass)
#pragma unroll
            for (int k = 0; k < NKW; ++k) {
                if ((validMask >> k) & 1u) sWay[tid + (k << 9)] = way[k];
            }
            // deferred dual updates (== e-maxx incremental totals), pre-augment;
            // popped columns have distinct assigned rows -> race-free.
#pragma unroll
            for (int k = 0; k < NKW; ++k) {
                if ((poppedM >> k) & 1u) {
                    const int q   = tid + (k << 9);
                    const int row = sP[q] - 1;
                    sU[row] += dT - minv[k];
                    v[k]    += minv[k] - dT;
                }
            }
            if (tid == 0) sU[rf] += dT;
            __syncthreads();
            if (tid == 0 && jT >= 0) {                // augment along parents
                int jj = jT, guard = 0;
                while (guard++ < 200) {
                    const int jp = sWay[jj];
                    if (jp < 0) { sP[jj] = rf + 1; break; }
                    sP[jj] = sP[jp];
                    jj = jp;
                }
            }
            __syncthreads();
        }
    }
    __syncthreads();

    // ---- extract matching: pred query for each target ----
    for (int q = tid; q < Q_; q += NTH) {
        const int pi = sP[q];
        if (pi > 0) sPred[pi - 1] = q;
    }
    __syncthreads();

    // ---- tc[] (reuse sWay): NUM_CLASSES default, matched queries get label ----
    int* sTc = sWay;
    for (int q = tid; q < Q_; q += NTH) sTc[q] = NCLS;
    __syncthreads();
    for (int t = tid; t < T_; t += NTH) sTc[sPred[t]] = sLab[t];  // sPred distinct
    __syncthreads();

    // ---- weighted CE over all queries ----
    double swn = 0.0, sw = 0.0;
    for (int q = tid; q < Q_; q += NTH) {
        const int   c   = sTc[q];
        const float xv  = pcb[q * NCLS1 + c];
        const float nll = sLse[q] - xv;              // -log_softmax[tc]
        const double w  = (c == NCLS) ? (double)0.05f : 1.0;
        swn += w * (double)nll;
        sw  += w;
    }

    // ---- bbox L1 + GIoU over matched pairs ----
    double l1s = 0.0, gs = 0.0;
    for (int t = tid; t < T_; t += NTH) {
        const int q = sPred[t];
        const float4 p4 = sPb4[q];
        const float4 t4 = sTb4[t];
        l1s += (double)fabsf(p4.x - t4.x) + (double)fabsf(p4.y - t4.y)
             + (double)fabsf(p4.z - t4.z) + (double)fabsf(p4.w - t4.w);
        const float ax1 = p4.x - 0.5f * p4.z, ay1 = p4.y - 0.5f * p4.w;
        const float ax2 = p4.x + 0.5f * p4.z, ay2 = p4.y + 0.5f * p4.w;
        const float bx1 = t4.x - 0.5f * t4.z, by1 = t4.y - 0.5f * t4.w;
        const float bx2 = t4.x + 0.5f * t4.z, by2 = t4.y + 0.5f * t4.w;
        const double a1 = (double)(ax2 - ax1) * (double)(ay2 - ay1);
        const double a2 = (double)(bx2 - bx1) * (double)(by2 - by1);
        const double ltx = fmax((double)ax1, (double)bx1);
        const double lty = fmax((double)ay1, (double)by1);
        const double rbx = fmin((double)ax2, (double)bx2);
        const double rby = fmin((double)ay2, (double)by2);
        const double iw = fmax(rbx - ltx, 0.0), ih = fmax(rby - lty, 0.0);
        const double inter = iw * ih;
        const double uni   = a1 + a2 - inter;
        const double iou   = inter / uni;
        const double cx1 = fmin((double)ax1, (double)bx1);
        const double cy1 = fmin((double)ay1, (double)by1);
        const double cx2 = fmax((double)ax2, (double)bx2);
        const double cy2 = fmax((double)ay2, (double)by2);
        const double ac  = (cx2 - cx1) * (cy2 - cy1);
        const double giou = iou - (ac - uni) / ac;
        gs += 1.0 - giou;
    }

    const double swnT = blockSum(swn, sAcc, tid);
    const double swT  = blockSum(sw,  sAcc, tid);
    const double l1T  = blockSum(l1s, sAcc, tid);
    const double gsT  = blockSum(gs,  sAcc, tid);
    if (tid == 0) {
        const double cls = swnT / swT;
        const double bb  = 5.0 * (l1T / (double)(T_ * 4)) + 2.0 * (gsT / (double)T_);
        const double mine = (cls + bb) / 8192.0;
        // fused finalize: CAS converts the 0xAA poison to 0.0 exactly once
        // (each block CASes before its own add; no spin), then atomic f32 sum.
        atomicCAS((unsigned int*)out, 0xAAAAAAAAu, 0u);
        atomicAdd(out, (float)mine);
    }
}

extern "C" void kernel_launch(void* const* d_in, const int* in_sizes, int n_in,
                              void* d_out, int out_size, void* d_ws, size_t ws_size,
                              hipStream_t stream) {
    const float* pc  = (const float*)d_in[0];   // predicted_class [64,900,14]
    const float* pbx = (const float*)d_in[1];   // predicted_bbox  [64,900,4]
    const int*   tl  = (const int*)  d_in[2];   // target_labels   [64,128]
    const float* tbx = (const float*)d_in[3];   // target_boxes    [64,128,4]
    (void)in_sizes; (void)n_in; (void)out_size; (void)d_ws; (void)ws_size;

    detr_hungarian_loss<<<dim3(B_), dim3(NTH), 0, stream>>>(pc, pbx, tl, tbx,
                                                            (float*)d_out);
}

// Round 12
// 107.852 us; speedup vs baseline: 1.2587x; 1.0002x over previous
//
#include <hip/hip_runtime.h>
#include <math.h>

// Problem constants (from reference): B=64, Q=900, T=128, NUM_CLASSES=13
#define B_    64
#define Q_    900
#define T_    128
#define NCLS  13
#define NCLS1 14
#define NTH   512
#define NWV   (NTH / 64)
#define NKW   2           // block-wide scan: col q = tid + 512*k, k<NKW

// Block-wide f64 sum; result valid on tid 0. All threads must call.
__device__ __forceinline__ double blockSum(double v, double* sAcc, int tid) {
#pragma unroll
    for (int off = 32; off > 0; off >>= 1) v += __shfl_down(v, off);
    if ((tid & 63) == 0) sAcc[tid >> 6] = v;
    __syncthreads();
    if (tid == 0) {
#pragma unroll
        for (int w = 1; w < NWV; ++w) v += sAcc[w];
    }
    __syncthreads();
    return v;
}

// f32 cost entry, identical op order to the jnp reference:
// (|dx|+|dy|+|dz|+|dw| summed left-to-right) - prob[lab].
__device__ __forceinline__ float costQ(const float4 p4, const float4 t4, const float pr) {
    float cb = fabsf(p4.x - t4.x);
    cb = cb + fabsf(p4.y - t4.y);
    cb = cb + fabsf(p4.z - t4.z);
    cb = cb + fabsf(p4.w - t4.w);
    return cb - pr;
}

// ---- DPP full-wave min reductions (row_shr + row_bcast chain) ----
// Verified exact on R11/R13/R16/R20/R23/R24/R25 (absmax 0).
#define DPP_ROW_SHR1 0x111
#define DPP_ROW_SHR2 0x112
#define DPP_ROW_SHR4 0x114
#define DPP_ROW_SHR8 0x118
#define DPP_BCAST15  0x142
#define DPP_BCAST31  0x143

__device__ __forceinline__ float waveMinF32(float x) {
    const int INFI = 0x7f800000;                       // +inf bits
    float f = x;
#define MRED(C) { const int o = __builtin_amdgcn_update_dpp(INFI, __float_as_int(f), C, 0xf, 0xf, false); \
                  f = fminf(f, __int_as_float(o)); }
    MRED(DPP_ROW_SHR1) MRED(DPP_ROW_SHR2) MRED(DPP_ROW_SHR4) MRED(DPP_ROW_SHR8)
    MRED(DPP_BCAST15)  MRED(DPP_BCAST31)
#undef MRED
    return __int_as_float(__builtin_amdgcn_readlane(__float_as_int(f), 63));
}

__device__ __forceinline__ int waveMinI32(int x) {
    int f = x;
#define MRED(C) { const int o = __builtin_amdgcn_update_dpp(0x7fffffff, f, C, 0xf, 0xf, false); \
                  f = (o < f) ? o : f; }
    MRED(DPP_ROW_SHR1) MRED(DPP_ROW_SHR2) MRED(DPP_ROW_SHR4) MRED(DPP_ROW_SHR8)
    MRED(DPP_BCAST15)  MRED(DPP_BCAST31)
#undef MRED
    return __builtin_amdgcn_readlane(f, 63);
}

// One block per image. History: R16/R19 94us; R20 69.4us; R23 58.4us;
// R24/R25 51.6us (absmax 0) = baseline. REVERTED/NULL: R17 (trajectory),
// R18/R21/R22 (pop-chain additions regress), R25 (sP-in-slot: null -> the
// sP read was already hidden; pop loop is at its structural floor: one
// barrier/pop is minimal, 6-step DPP is the minimal 64-lane reduce).
// This round (R26): staging loads vectorized as float2 (q*56B is 8-aligned
// for all q) -> 7 VMEM issues/thread instead of 14 during the staging
// phase. Bits identical, unpack order identical => absmax 0.
extern "C" __global__ __launch_bounds__(NTH, 1)
void detr_hungarian_loss(const float* __restrict__ pc,    // [B,Q,14]
                         const float* __restrict__ pbx,   // [B,Q,4]
                         const int*   __restrict__ tl,    // [B,T]
                         const float* __restrict__ tbx,   // [B,T,4]
                         float* __restrict__ out)         // [1], poisoned 0xAA
{
    const int b   = blockIdx.x;
    const int tid = threadIdx.x;

    __shared__ float  sProb[Q_ * NCLS];   // softmax probs, classes 0..12
    __shared__ float  sLse[Q_];           // logsumexp per query (for CE)
    __shared__ float4 sPb4[Q_];           // predicted boxes
    __shared__ float4 sTb4[T_];           // target boxes
    __shared__ int    sLab[T_];           // target labels
    __shared__ float  sU[T_];             // row duals (f32)
    __shared__ int    sP[Q_];             // col -> row+1, 0 = free
    __shared__ int    sWay[Q_];           // parent cols (per pass); scratch: minrow; reused as tc[]
    __shared__ int    sAmin[T_];          // row -> argmin column
    __shared__ int    sFree[T_];
    __shared__ int    sNF;
    __shared__ int    sWcnt[2];           // per-wave free counts (greedy init)
    __shared__ int    sPred[T_];          // target t -> matched query
    __shared__ unsigned long long sSlot[4]; // packed pop minima, round-robin
    __shared__ double sAcc[NWV];

    const float FINF = __builtin_inff();

    const float* pcb = pc  + (size_t)b * Q_ * NCLS1;
    const float* pbb = pbx + (size_t)b * Q_ * 4;
    const float* tbb = tbx + (size_t)b * T_ * 4;
    const int*   tlb = tl  + (size_t)b * T_;

    // ---- stage inputs + f32 softmax (same op order as jax.nn.softmax).
    // Logits loaded as 7x float2 (8B-aligned for every q); identical bits,
    // identical unpack order as the scalar version. ----
    const float2* pcb2 = reinterpret_cast<const float2*>(pcb);
    for (int q = tid; q < Q_; q += NTH) {
        float2 xv2[7];
#pragma unroll
        for (int j = 0; j < 7; ++j) xv2[j] = pcb2[q * 7 + j];
        float x[NCLS1];
#pragma unroll
        for (int j = 0; j < 7; ++j) { x[2 * j] = xv2[j].x; x[2 * j + 1] = xv2[j].y; }
        float mx = x[0];
#pragma unroll
        for (int c = 1; c < NCLS1; ++c) mx = fmaxf(mx, x[c]);
        float ex[NCLS1];
        float sum = 0.f;
#pragma unroll
        for (int c = 0; c < NCLS1; ++c) { ex[c] = expf(x[c] - mx); sum += ex[c]; }
#pragma unroll
        for (int c = 0; c < NCLS; ++c) sProb[q * NCLS + c] = ex[c] / sum;
        sLse[q] = mx + logf(sum);
        sPb4[q] = reinterpret_cast<const float4*>(pbb)[q];
        sP[q] = 0;
        sWay[q] = 0x7fffffff;             // minrow scratch for greedy init
    }
    for (int t = tid; t < T_; t += NTH) {
        sLab[t] = tlb[t];
        sTb4[t] = reinterpret_cast<const float4*>(tbb)[t];
    }
    __syncthreads();

    // ---- phase 1: row minima u[r] = min_j cost[r][j] + argmin column.
    // 4 threads per row, 225 cols each; xor(1)+xor(2) combine with the same
    // value-then-smallest-q tie-break => identical (u, argmin) as serial. ----
    {
        const int r  = tid >> 2;          // 0..127
        const int qt = tid & 3;
        const float4 t4  = sTb4[r];
        const int    lab = sLab[r];
        float bv = FINF;
        int   bj = Q_;
        const int q0 = qt * (Q_ / 4);
        for (int q = q0; q < q0 + (Q_ / 4); ++q) {
            const float c = costQ(sPb4[q], t4, sProb[q * NCLS + lab]);
            if (c < bv) { bv = c; bj = q; }
        }
#pragma unroll
        for (int d = 1; d <= 2; d <<= 1) {
            const float ov = __shfl_xor(bv, d);
            const int   oj = __shfl_xor(bj, d);
            if (ov < bv || (ov == bv && oj < bj)) { bv = ov; bj = oj; }
        }
        if (qt == 0) { sU[r] = bv; sAmin[r] = bj; }
    }
    __syncthreads();

    // ---- greedy zero-reduced-cost assignment (parallel, serial-equivalent;
    // verified exact R16/R19/R20/R23/R24/R25): row r wins col sAmin[r] iff r
    // is the min proposing row. Free list in increasing r via ballot prefix. ----
    bool isfree = false; int fpos = 0;
    if (tid < T_) atomicMin(&sWay[sAmin[tid]], tid);
    __syncthreads();
    if (tid < T_) {
        const int j = sAmin[tid];
        isfree = (sWay[j] != tid);
        if (!isfree) sP[j] = tid + 1;
        const unsigned long long bal = __ballot(isfree);
        const int lane = tid & 63;
        fpos = __popcll(bal & ((1ull << (unsigned)lane) - 1ull));
        if (lane == 0) sWcnt[tid >> 6] = (int)__popcll(bal);
    }
    __syncthreads();
    if (tid < T_ && isfree) {
        const int off = (tid >> 6) ? sWcnt[0] : 0;
        sFree[off + fpos] = tid;
    }
    if (tid == 0) sNF = sWcnt[0] + sWcnt[1];
    __syncthreads();

    // ============ block-wide deferred-dual SSP (all 8 waves scan) ============
    {
        const int lane = tid & 63;
        unsigned validMask = 0;
#pragma unroll
        for (int k = 0; k < NKW; ++k)
            if (tid + (k << 9) < Q_) validMask |= 1u << k;

        float4 pbq[NKW];                  // owned predicted boxes
        float  v[NKW];                    // owned column duals
#pragma unroll
        for (int k = 0; k < NKW; ++k) {
            const int q = tid + (k << 9);
            pbq[k] = (q < Q_) ? sPb4[q] : make_float4(0.f, 0.f, 0.f, 0.f);
            v[k] = 0.f;
        }
        const int nf = sNF;

        for (int fi = 0; fi < nf; ++fi) {
            const int rf = sFree[fi];
            float minv[NKW];
            int   way[NKW];
#pragma unroll
            for (int k = 0; k < NKW; ++k) { minv[k] = FINF; way[k] = -1; }
            unsigned usedM   = ~validMask & ((1u << NKW) - 1u);
            unsigned poppedM = 0;
            int   i0row = rf;
            float dcur  = 0.f;
            int   jprev = -1;             // root marker
            float dT = 0.f; int jT = -1;

            if (tid < 4) sSlot[tid] = ~0ull;   // arm all 4 slots
            __syncthreads();

            for (int it = 0; it < 200; ++it) {
                const int    buf  = it & 3;
                const float  u0   = sU[i0row];
                const float4 t4   = sTb4[i0row];
                const int    lab  = sLab[i0row];
                const float  base = dcur - u0;

                float bestv = FINF;
                int   bestq = 1 << 29;
#pragma unroll
                for (int k = 0; k < NKW; ++k) {
                    if (!((usedM >> k) & 1u)) {
                        const int   q    = tid + (k << 9);
                        const float cost = costQ(pbq[k], t4, sProb[q * NCLS + lab]);
                        const float cur  = base + (cost - v[k]);   // R6 association
                        if (cur < minv[k]) { minv[k] = cur; way[k] = jprev; }
                        if (minv[k] < bestv) { bestv = minv[k]; bestq = q; }
                    }
                }
                // per-lane sP prefetch of own best column: issued here so its
                // ~50cy latency hides under the DPP reduce. sP is constant
                // inside the pop loop, so values are exact.
                const int myrow = sP[((unsigned)bestq < (unsigned)Q_) ? bestq : 0];
                // per-wave min: DPP value-min + ballot fast path; ties ->
                // exact i32 DPP min (smallest column within the wave).
                const float wval = waveMinF32(bestv);
                const unsigned long long tm = __ballot(bestv == wval);
                int wq, wrow;
                if (__popcll(tm) == 1) {
                    const int wl = (int)__builtin_ctzll(tm);
                    wq   = __builtin_amdgcn_readlane(bestq, wl);
                    wrow = __builtin_amdgcn_readlane(myrow, wl);
                } else {
                    const int cand = (bestv == wval) ? bestq : 0x7fffffff;
                    wq = waveMinI32(cand);
                    const unsigned long long tw =
                        __ballot(bestv == wval && bestq == wq);
                    const int wl = (int)__builtin_ctzll(tw);
                    wrow = __builtin_amdgcn_readlane(myrow, wl);
                }
                if (lane == 0) {
                    // monotone f32->u32 key; +-0.0 share one key so float-
                    // equality ties still resolve to the smallest column.
                    const unsigned s = __float_as_uint(wval);
                    const unsigned key = (s == 0x80000000u) ? 0x80000000u
                                       : ((s & 0x80000000u) ? ~s : (s | 0x80000000u));
                    const unsigned long long pk =
                        ((unsigned long long)key << 32) |
                        ((unsigned long long)((unsigned)wq & 0xFFFFFFu) << 8) |
                        (unsigned long long)((unsigned)wrow & 0xFFu);
                    atomicMin(&sSlot[buf], pk);
                }
                if (tid == 0) sSlot[(it + 2) & 3] = ~0ull;  // re-arm (safe slot)
                __syncthreads();
                // global winner: ONE broadcast read; u64 min == (min value,
                // smallest q) lexicographic == np.argmin semantics; rowm
                // rides along (same column => same rowm on ties).
                const unsigned long long m = sSlot[buf];
                const unsigned kk   = (unsigned)(m >> 32);
                const int      winq = (int)((m >> 8) & 0xFFFFFFull);
                const int      rowm = (int)(m & 0xFFull);
                const float    winv = __uint_as_float(
                    (kk & 0x80000000u) ? (kk ^ 0x80000000u) : ~kk);

                if (tid == (winq & (NTH - 1))) usedM |= 1u << (winq >> 9);  // freeze
                if (rowm == 0) { dT = winv; jT = winq; break; }   // free col: done
                if (tid == (winq & (NTH - 1))) poppedM |= 1u << (winq >> 9);
                jprev = winq; i0row = rowm - 1; dcur = winv;
            }

            // flush way regs (augment only reads cols improved this pass)
#pragma unroll
            for (int k = 0; k < NKW; ++k) {
                if ((validMask >> k) & 1u) sWay[tid + (k << 9)] = way[k];
            }
            // deferred dual updates (== e-maxx incremental totals), pre-augment;
            // popped columns have distinct assigned rows -> race-free.
#pragma unroll
            for (int k = 0; k < NKW; ++k) {
                if ((poppedM >> k) & 1u) {
                    const int q   = tid + (k << 9);
                    const int row = sP[q] - 1;
                    sU[row] += dT - minv[k];
                    v[k]    += minv[k] - dT;
                }
            }
            if (tid == 0) sU[rf] += dT;
            __syncthreads();
            if (tid == 0 && jT >= 0) {                // augment along parents
                int jj = jT, guard = 0;
                while (guard++ < 200) {
                    const int jp = sWay[jj];
                    if (jp < 0) { sP[jj] = rf + 1; break; }
                    sP[jj] = sP[jp];
                    jj = jp;
                }
            }
            __syncthreads();
        }
    }
    __syncthreads();

    // ---- extract matching: pred query for each target ----
    for (int q = tid; q < Q_; q += NTH) {
        const int pi = sP[q];
        if (pi > 0) sPred[pi - 1] = q;
    }
    __syncthreads();

    // ---- tc[] (reuse sWay): NUM_CLASSES default, matched queries get label ----
    int* sTc = sWay;
    for (int q = tid; q < Q_; q += NTH) sTc[q] = NCLS;
    __syncthreads();
    for (int t = tid; t < T_; t += NTH) sTc[sPred[t]] = sLab[t];  // sPred distinct
    __syncthreads();

    // ---- weighted CE over all queries ----
    double swn = 0.0, sw = 0.0;
    for (int q = tid; q < Q_; q += NTH) {
        const int   c   = sTc[q];
        const float xv  = pcb[q * NCLS1 + c];
        const float nll = sLse[q] - xv;              // -log_softmax[tc]
        const double w  = (c == NCLS) ? (double)0.05f : 1.0;
        swn += w * (double)nll;
        sw  += w;
    }

    // ---- bbox L1 + GIoU over matched pairs ----
    double l1s = 0.0, gs = 0.0;
    for (int t = tid; t < T_; t += NTH) {
        const int q = sPred[t];
        const float4 p4 = sPb4[q];
        const float4 t4 = sTb4[t];
        l1s += (double)fabsf(p4.x - t4.x) + (double)fabsf(p4.y - t4.y)
             + (double)fabsf(p4.z - t4.z) + (double)fabsf(p4.w - t4.w);
        const float ax1 = p4.x - 0.5f * p4.z, ay1 = p4.y - 0.5f * p4.w;
        const float ax2 = p4.x + 0.5f * p4.z, ay2 = p4.y + 0.5f * p4.w;
        const float bx1 = t4.x - 0.5f * t4.z, by1 = t4.y - 0.5f * t4.w;
        const float bx2 = t4.x + 0.5f * t4.z, by2 = t4.y + 0.5f * t4.w;
        const double a1 = (double)(ax2 - ax1) * (double)(ay2 - ay1);
        const double a2 = (double)(bx2 - bx1) * (double)(by2 - by1);
        const double ltx = fmax((double)ax1, (double)bx1);
        const double lty = fmax((double)ay1, (double)by1);
        const double rbx = fmin((double)ax2, (double)bx2);
        const double rby = fmin((double)ay2, (double)by2);
        const double iw = fmax(rbx - ltx, 0.0), ih = fmax(rby - lty, 0.0);
        const double inter = iw * ih;
        const double uni   = a1 + a2 - inter;
        const double iou   = inter / uni;
        const double cx1 = fmin((double)ax1, (double)bx1);
        const double cy1 = fmin((double)ay1, (double)by1);
        const double cx2 = fmax((double)ax2, (double)bx2);
        const double cy2 = fmax((double)ay2, (double)by2);
        const double ac  = (cx2 - cx1) * (cy2 - cy1);
        const double giou = iou - (ac - uni) / ac;
        gs += 1.0 - giou;
    }

    const double swnT = blockSum(swn, sAcc, tid);
    const double swT  = blockSum(sw,  sAcc, tid);
    const double l1T  = blockSum(l1s, sAcc, tid);
    const double gsT  = blockSum(gs,  sAcc, tid);
    if (tid == 0) {
        const double cls = swnT / swT;
        const double bb  = 5.0 * (l1T / (double)(T_ * 4)) + 2.0 * (gsT / (double)T_);
        const double mine = (cls + bb) / 8192.0;
        // fused finalize: CAS converts the 0xAA poison to 0.0 exactly once
        // (each block CASes before its own add; no spin), then atomic f32 sum.
        atomicCAS((unsigned int*)out, 0xAAAAAAAAu, 0u);
        atomicAdd(out, (float)mine);
    }
}

extern "C" void kernel_launch(void* const* d_in, const int* in_sizes, int n_in,
                              void* d_out, int out_size, void* d_ws, size_t ws_size,
                              hipStream_t stream) {
    const float* pc  = (const float*)d_in[0];   // predicted_class [64,900,14]
    const float* pbx = (const float*)d_in[1];   // predicted_bbox  [64,900,4]
    const int*   tl  = (const int*)  d_in[2];   // target_labels   [64,128]
    const float* tbx = (const float*)d_in[3];   // target_boxes    [64,128,4]
    (void)in_sizes; (void)n_in; (void)out_size; (void)d_ws; (void)ws_size;

    detr_hungarian_loss<<<dim3(B_), dim3(NTH), 0, stream>>>(pc, pbx, tl, tbx,
                                                            (float*)d_out);
}